// Round 7
// baseline (1004.248 us; speedup 1.0000x reference)
//
#include <hip/hip_runtime.h>
#include <cstdint>
#include <cstddef>

#define DD 768
#define SS 128
#define NNODE 12288            // 3*B*S
#define NBS 4096               // B*S
#define NBSD 3145728           // B*S*D (per-chunk elements)
#define TOTAL_ND 9437184ULL    // NNODE*DD == out_size (fp32 elements)
#define WMAT 589824            // 768*768
#define WSLOT 1179648          // hi+lo pair of one 768x768 matrix (u16 elems)

typedef __attribute__((ext_vector_type(4))) float f32x4;
typedef __attribute__((ext_vector_type(8))) short bf16x8;
typedef __attribute__((ext_vector_type(4))) uint16_t u16x4;
typedef __attribute__((ext_vector_type(2))) uint16_t u16x2;
typedef __attribute__((ext_vector_type(8))) uint16_t u16x8;
typedef __attribute__((ext_vector_type(2))) uint32_t u32x2;

__device__ __forceinline__ float b2f(uint16_t u) {
    union { uint32_t i; float f; } x; x.i = ((uint32_t)u) << 16; return x.f;
}
__device__ __forceinline__ uint16_t f2b(float f) {
    uint32_t x = __float_as_uint(f);
    return (uint16_t)((x + 0x7FFFu + ((x >> 16) & 1u)) >> 16);
}
__device__ __forceinline__ float loadf(const void* p, size_t i, int isf32) {
    return isf32 ? ((const float*)p)[i] : b2f(((const uint16_t*)p)[i]);
}
// feats[n][d] = src_{d%3}[n*256 + d/3]
__device__ __forceinline__ float featAt(const void* hc, const void* hd, const void* hs,
                                        int n, int d, int isf) {
    int w = d % 3;
    size_t u = (size_t)n * 256 + (size_t)(d / 3);
    const void* p = (w == 0) ? hc : (w == 1) ? hd : hs;
    return loadf(p, u, isf);
}
__device__ __forceinline__ uint32_t pk2(uint16_t a, uint16_t b) {
    return (uint32_t)a | ((uint32_t)b << 16);
}

// async 16B global->LDS (linear dest: wave-uniform base + lane*16)
__device__ __forceinline__ void gload16(const uint16_t* g, uint16_t* l) {
    __builtin_amdgcn_global_load_lds(
        (__attribute__((address_space(1))) uint32_t*)(uintptr_t)g,
        (__attribute__((address_space(3))) uint32_t*)l, 16, 0, 0);
}

// ---------- diag beacon ----------
__global__ void k_diag(float* out, float code) {
    if (threadIdx.x == 0 && blockIdx.x == 0) out[0] = code;
}

// ---------- dtype probe ----------
__global__ void k_probe(const void* hf, int* flag) {
    if (threadIdx.x == 0 && blockIdx.x == 0) {
        const uint32_t* w = (const uint32_t*)hf;
        int bad = 0;
        for (int k = 0; k < 64; k++) {
            uint16_t lo = (uint16_t)(w[k] & 0xFFFFu);
            int e = (lo >> 7) & 0xFF;
            if (e < 100 || e > 140) bad++;
        }
        flag[0] = (bad > 24) ? 1 : 0;
    }
}

// ---------- feats build + F128 hi/lo split (merged) ----------
__global__ __launch_bounds__(256) void k_build_all(
    const void* __restrict__ hc, const void* __restrict__ hd,
    const void* __restrict__ hs, uint16_t* __restrict__ feats,
    uint16_t* __restrict__ Fh, uint16_t* __restrict__ Fl,
    const int* __restrict__ flag) {
    int isf = flag[0];
    if (blockIdx.x < 3072) {
        int u = (blockIdx.x * 256 + threadIdx.x) * 4;
        float a[4], b[4], c[4];
        if (isf) {
            f32x4 va = *(const f32x4*)((const float*)hc + u);
            f32x4 vb = *(const f32x4*)((const float*)hd + u);
            f32x4 vc = *(const f32x4*)((const float*)hs + u);
            #pragma unroll
            for (int q = 0; q < 4; q++) { a[q] = va[q]; b[q] = vb[q]; c[q] = vc[q]; }
        } else {
            u16x4 va = *(const u16x4*)((const uint16_t*)hc + u);
            u16x4 vb = *(const u16x4*)((const uint16_t*)hd + u);
            u16x4 vc = *(const u16x4*)((const uint16_t*)hs + u);
            #pragma unroll
            for (int q = 0; q < 4; q++) { a[q] = b2f(va[q]); b[q] = b2f(vb[q]); c[q] = b2f(vc[q]); }
        }
        uint16_t o[12];
        #pragma unroll
        for (int q = 0; q < 4; q++) {
            o[3 * q] = f2b(a[q]); o[3 * q + 1] = f2b(b[q]); o[3 * q + 2] = f2b(c[q]);
        }
        u32x2 w0 = {pk2(o[0], o[1]), pk2(o[2], o[3])};
        u32x2 w1 = {pk2(o[4], o[5]), pk2(o[6], o[7])};
        u32x2 w2 = {pk2(o[8], o[9]), pk2(o[10], o[11])};
        *(u32x2*)(feats + (size_t)3 * u) = w0;
        *(u32x2*)(feats + (size_t)3 * u + 4) = w1;
        *(u32x2*)(feats + (size_t)3 * u + 8) = w2;
    } else {
        int t = (blockIdx.x - 3072) * 256 + threadIdx.x;   // 384 blocks -> 98304
        int n = t / DD, d = t - n * DD;
        float v = featAt(hc, hd, hs, n, d, isf);
        uint16_t h = f2b(v);
        Fh[t] = h;
        Fl[t] = f2b(v - b2f(h));
    }
}

// ---------- G = F F^T via MFMA hi/lo (drops ll term, ~1e-5 rel err) ----------
__global__ __launch_bounds__(256)
void k_simgemm(const uint16_t* __restrict__ Fh, const uint16_t* __restrict__ Fl,
               float* __restrict__ G) {
    __shared__ __align__(16) uint16_t Ah[64 * 32], Al[64 * 32], Bh_[64 * 32], Bl_[64 * 32];
    const int tid = threadIdx.x, lane = tid & 63, wid = tid >> 6;
    const int wr = wid >> 1, wc = wid & 1;
    const int m0 = blockIdx.y * 64, n0 = blockIdx.x * 64;
    f32x4 acc[2][2];
    #pragma unroll
    for (int i = 0; i < 2; i++)
        #pragma unroll
        for (int j = 0; j < 2; j++) acc[i][j] = (f32x4){0.f, 0.f, 0.f, 0.f};
    const int sr = tid >> 2, sg = tid & 3;
    const int sgl = sg ^ ((sr >> 1) & 3);
    const int dofs = wid * 64 * 8;
    for (int k0 = 0; k0 < DD; k0 += 32) {
        gload16(Fh + (size_t)(m0 + sr) * DD + k0 + sgl * 8, Ah + dofs);
        gload16(Fl + (size_t)(m0 + sr) * DD + k0 + sgl * 8, Al + dofs);
        gload16(Fh + (size_t)(n0 + sr) * DD + k0 + sgl * 8, Bh_ + dofs);
        gload16(Fl + (size_t)(n0 + sr) * DD + k0 + sgl * 8, Bl_ + dofs);
        __syncthreads();
        bf16x8 ah[2], al[2], bh2[2], bl2[2];
        #pragma unroll
        for (int i = 0; i < 2; i++) {
            int r = wr * 32 + i * 16 + (lane & 15);
            int g = (lane >> 4) ^ ((r >> 1) & 3);
            ah[i] = *(const bf16x8*)(Ah + r * 32 + g * 8);
            al[i] = *(const bf16x8*)(Al + r * 32 + g * 8);
        }
        #pragma unroll
        for (int j = 0; j < 2; j++) {
            int r = wc * 32 + j * 16 + (lane & 15);
            int g = (lane >> 4) ^ ((r >> 1) & 3);
            bh2[j] = *(const bf16x8*)(Bh_ + r * 32 + g * 8);
            bl2[j] = *(const bf16x8*)(Bl_ + r * 32 + g * 8);
        }
        #pragma unroll
        for (int i = 0; i < 2; i++)
            #pragma unroll
            for (int j = 0; j < 2; j++)
                acc[i][j] = __builtin_amdgcn_mfma_f32_16x16x32_bf16(ah[i], bh2[j], acc[i][j], 0, 0, 0);
        #pragma unroll
        for (int i = 0; i < 2; i++)
            #pragma unroll
            for (int j = 0; j < 2; j++)
                acc[i][j] = __builtin_amdgcn_mfma_f32_16x16x32_bf16(ah[i], bl2[j], acc[i][j], 0, 0, 0);
        #pragma unroll
        for (int i = 0; i < 2; i++)
            #pragma unroll
            for (int j = 0; j < 2; j++)
                acc[i][j] = __builtin_amdgcn_mfma_f32_16x16x32_bf16(al[i], bh2[j], acc[i][j], 0, 0, 0);
        __syncthreads();
    }
    #pragma unroll
    for (int i = 0; i < 2; i++)
        #pragma unroll
        for (int j = 0; j < 2; j++) {
            int n = n0 + wc * 32 + j * 16 + (lane & 15);
            int mb = m0 + wr * 32 + i * 16 + ((lane >> 4) << 2);
            #pragma unroll
            for (int q = 0; q < 4; q++)
                G[(size_t)(mb + q) * SS + n] = acc[i][j][q];
        }
}

// ---------- sim post: nrm from diag -> cos normalize (in place) -> minmax ----------
__global__ __launch_bounds__(256) void k_simpost(float* __restrict__ simb,
                                                 float* __restrict__ mnmx) {
    int tid = threadIdx.x;
    __shared__ float nrmS[SS];
    if (tid < SS) nrmS[tid] = fmaxf(sqrtf(simb[(size_t)tid * SS + tid]), 1e-8f);
    __syncthreads();
    float mn = 3.4e38f, mx = -3.4e38f;
    for (int e = tid; e < SS * SS; e += 256) {
        int i = e >> 7, j = e & 127;
        float v = simb[e] / (nrmS[i] * nrmS[j]);
        simb[e] = v;
        mn = fminf(mn, v); mx = fmaxf(mx, v);
    }
    __shared__ float rmn[256], rmx[256];
    rmn[tid] = mn; rmx[tid] = mx; __syncthreads();
    for (int o = 128; o > 0; o >>= 1) {
        if (tid < o) { rmn[tid] = fminf(rmn[tid], rmn[tid + o]); rmx[tid] = fmaxf(rmx[tid], rmx[tid + o]); }
        __syncthreads();
    }
    if (tid == 0) { mnmx[0] = rmn[0]; mnmx[1] = rmx[0]; }
}

// ---------- min-max normalize sims in place, deg/dinv ----------
__global__ __launch_bounds__(128) void k_deg(float* __restrict__ simb,
                                             const float* __restrict__ mnmx,
                                             float* __restrict__ deg,
                                             float* __restrict__ dinv) {
    int j = blockIdx.x, i = threadIdx.x;
    float mn = mnmx[0], inv = 1.f / (mnmx[1] - mnmx[0]);
    float s = (simb[i * SS + j] - mn) * inv;
    simb[i * SS + j] = s;
    __shared__ float red[128];
    red[i] = s; __syncthreads();
    for (int o = 64; o > 0; o >>= 1) { if (i < o) red[i] += red[i + o]; __syncthreads(); }
    if (i == 0) { float d = red[0] + 1.f; deg[j] = d; dinv[j] = rsqrtf(d); }
}

// ---------- GCN neighbor aggregate (j<128), grid (SS,3) ----------
__global__ __launch_bounds__(256) void k_agg(const float* __restrict__ simb,
                                             const float* __restrict__ dinv,
                                             const uint16_t* __restrict__ xw,
                                             float* __restrict__ aggb) {
    int j = blockIdx.x;
    int d = blockIdx.y * 256 + threadIdx.x;
    __shared__ float w[SS];
    if (threadIdx.x < SS) w[threadIdx.x] = dinv[threadIdx.x] * simb[threadIdx.x * SS + j] * dinv[j];
    __syncthreads();
    float s = 0.f;
    #pragma unroll 8
    for (int i = 0; i < SS; i++) s += w[i] * b2f(xw[(size_t)i * DD + d]);
    aggb[(size_t)j * DD + d] = s;
}

// ---------- GCN combine in place (vec x8, bf16 state) ----------
__global__ __launch_bounds__(256) void k_gcn_combine(uint16_t* __restrict__ xw,
                                                     const float* __restrict__ aggb,
                                                     const float* __restrict__ deg,
                                                     const void* __restrict__ gcnb,
                                                     const int* __restrict__ flag) {
    uint32_t t = (blockIdx.x * 256 + threadIdx.x) * 8u;   // 4608 blocks, exact
    int isf = flag[0];
    uint32_t n = t / 768u;
    uint32_t d0 = t - n * 768u;
    u16x8 xv = *(const u16x8*)(xw + t);
    float v[8];
    #pragma unroll
    for (int q = 0; q < 8; q++) v[q] = b2f(xv[q]);
    if (n < SS) {
        f32x4 a0 = *(const f32x4*)(aggb + t);
        f32x4 a1 = *(const f32x4*)(aggb + t + 4);
        float dg = deg[n];
        #pragma unroll
        for (int q = 0; q < 4; q++) { v[q] = v[q] / dg + a0[q]; v[q + 4] = v[q + 4] / dg + a1[q]; }
    }
    float bb[8];
    if (isf) {
        f32x4 b0 = *(const f32x4*)((const float*)gcnb + d0);
        f32x4 b1 = *(const f32x4*)((const float*)gcnb + d0 + 4);
        #pragma unroll
        for (int q = 0; q < 4; q++) { bb[q] = b0[q]; bb[q + 4] = b1[q]; }
    } else {
        u16x8 b8 = *(const u16x8*)((const uint16_t*)gcnb + d0);
        #pragma unroll
        for (int q = 0; q < 8; q++) bb[q] = b2f(b8[q]);
    }
    u16x8 ov;
    #pragma unroll
    for (int q = 0; q < 8; q++) ov[q] = f2b(fmaxf(v[q] + bb[q], 0.f));
    *(u16x8*)(xw + t) = ov;
}

// ---------- colsum over first 128 rows (12 blocks, 4-way row split) ----------
__global__ __launch_bounds__(256) void k_colsum(const uint16_t* __restrict__ x,
                                                float* __restrict__ svec) {
    int d = blockIdx.x * 64 + (threadIdx.x & 63);
    int part = threadIdx.x >> 6;
    float s = 0.f;
    for (int i = part * 32; i < part * 32 + 32; i++) s += b2f(x[(size_t)i * DD + d]);
    __shared__ float red[256];
    red[threadIdx.x] = s; __syncthreads();
    if (part == 0)
        svec[d] = red[threadIdx.x] + red[threadIdx.x + 64] +
                  red[threadIdx.x + 128] + red[threadIdx.x + 192];
}

// ---------- mvec = svec @ ggc_W[l] ----------
__global__ __launch_bounds__(256) void k_matvec(const float* __restrict__ svec,
                                                const void* __restrict__ Wg, size_t ofs,
                                                float* __restrict__ mvec,
                                                const int* __restrict__ flag) {
    int k = blockIdx.x * 256 + threadIdx.x;
    int isf = flag[0];
    if (k < DD) {
        float s = 0.f;
        for (int d = 0; d < DD; d++) s += svec[d] * loadf(Wg, ofs + (size_t)d * DD + k, isf);
        mvec[k] = s;
    }
}

// ---------- giE = mvec @ wih.T + bih ----------
__global__ __launch_bounds__(256) void k_rowdot(const float* __restrict__ mvec,
                                                const void* __restrict__ wih,
                                                const void* __restrict__ bih,
                                                float* __restrict__ giE,
                                                const int* __restrict__ flag) {
    int rr = blockIdx.x, tid = threadIdx.x;
    int isf = flag[0];
    float s = 0.f;
    for (int k = tid; k < DD; k += 256) s += mvec[k] * loadf(wih, (size_t)rr * DD + k, isf);
    __shared__ float red[256];
    red[tid] = s; __syncthreads();
    for (int o = 128; o > 0; o >>= 1) { if (tid < o) red[tid] += red[tid + o]; __syncthreads(); }
    if (tid == 0) giE[rr] = red[0] + loadf(bih, rr, isf);
}

// ---------- y = h_feature + relu(x_g), batched all 3 chunks, vec x8 ----------
__global__ __launch_bounds__(256) void k_build_y(const void* __restrict__ hf,
                                                 const uint16_t* __restrict__ xg,
                                                 uint16_t* __restrict__ y,
                                                 const int* __restrict__ flag) {
    uint32_t t = (blockIdx.x * 256 + threadIdx.x) * 8u;   // 4608 blocks, exact TOTAL_ND
    int isf = flag[0];
    uint32_t u = t;
    if (u >= 2u * NBSD) u -= 2u * NBSD; else if (u >= NBSD) u -= NBSD;
    u16x8 xv = *(const u16x8*)(xg + t);
    float h[8];
    if (isf) {
        f32x4 h0 = *(const f32x4*)((const float*)hf + u);
        f32x4 h1 = *(const f32x4*)((const float*)hf + u + 4);
        #pragma unroll
        for (int q = 0; q < 4; q++) { h[q] = h0[q]; h[q + 4] = h1[q]; }
    } else {
        u16x8 h8 = *(const u16x8*)((const uint16_t*)hf + u);
        #pragma unroll
        for (int q = 0; q < 8; q++) h[q] = b2f(h8[q]);
    }
    u16x8 ov;
    #pragma unroll
    for (int q = 0; q < 8; q++) ov[q] = f2b(h[q] + fmaxf(b2f(xv[q]), 0.f));
    *(u16x8*)(y + t) = ov;
}

// ---------- LayerNorm (batched: 12288 rows, per-g weight select) ----------
__global__ __launch_bounds__(256) void k_ln(const uint16_t* __restrict__ tin,
                                            const void* g0, const void* b0,
                                            const void* g1, const void* b1,
                                            const void* g2, const void* b2,
                                            float* __restrict__ out,
                                            const int* __restrict__ flag) {
    int m = blockIdx.x, tid = threadIdx.x;
    int isf = flag[0];
    int gs = m >> 12;
    const void* gw = (gs == 0) ? g0 : (gs == 1) ? g1 : g2;
    const void* bw = (gs == 0) ? b0 : (gs == 1) ? b1 : b2;
    float v0 = b2f(tin[(size_t)m * DD + tid]);
    float v1 = b2f(tin[(size_t)m * DD + tid + 256]);
    float v2 = b2f(tin[(size_t)m * DD + tid + 512]);
    __shared__ float red[256];
    red[tid] = v0 + v1 + v2; __syncthreads();
    for (int o = 128; o > 0; o >>= 1) { if (tid < o) red[tid] += red[tid + o]; __syncthreads(); }
    float mu = red[0] * (1.f / 768.f);
    __syncthreads();
    float d0 = v0 - mu, d1 = v1 - mu, d2 = v2 - mu;
    red[tid] = d0 * d0 + d1 * d1 + d2 * d2; __syncthreads();
    for (int o = 128; o > 0; o >>= 1) { if (tid < o) red[tid] += red[tid + o]; __syncthreads(); }
    float rstd = rsqrtf(red[0] * (1.f / 768.f) + 1e-5f);
    out[(size_t)m * DD + tid]       = d0 * rstd * loadf(gw, tid, isf)       + loadf(bw, tid, isf);
    out[(size_t)m * DD + tid + 256] = d1 * rstd * loadf(gw, tid + 256, isf) + loadf(bw, tid + 256, isf);
    out[(size_t)m * DD + tid + 512] = d2 * rstd * loadf(gw, tid + 512, isf) + loadf(bw, tid + 512, isf);
}

// ---------- weight convert: hi/lo bf16 split, elementwise vec x4 ----------
__global__ __launch_bounds__(256) void k_cvt2(const void* __restrict__ src,
                                              uint16_t* __restrict__ dh,
                                              uint16_t* __restrict__ dl, int n,
                                              const int* __restrict__ flag) {
    int t = (blockIdx.x * 256 + threadIdx.x) * 4;   // exact cover
    int isf = flag[0];
    float v[4];
    if (isf) {
        f32x4 s = *(const f32x4*)((const float*)src + t);
        #pragma unroll
        for (int q = 0; q < 4; q++) v[q] = s[q];
    } else {
        u16x4 s = *(const u16x4*)((const uint16_t*)src + t);
        #pragma unroll
        for (int q = 0; q < 4; q++) v[q] = b2f(s[q]);
    }
    u16x4 hh, ll;
    #pragma unroll
    for (int q = 0; q < 4; q++) {
        uint16_t h = f2b(v[q]);
        hh[q] = h;
        ll[q] = f2b(v[q] - b2f(h));
    }
    *(u16x4*)(dh + t) = hh;
    *(u16x4*)(dl + t) = ll;
}

// ---------- weight convert: transpose + hi/lo split, 7 matrices batched ----------
__global__ __launch_bounds__(256) void k_cvtT7(const void* s0, const void* s1,
                                               const void* s2, const void* s3,
                                               const void* s4, const void* s5,
                                               const void* s6,
                                               uint16_t* __restrict__ gdst,
                                               uint16_t* __restrict__ tail,
                                               const int* __restrict__ flag) {
    __shared__ float tile[64][65];
    int isf = flag[0];
    int z = blockIdx.z;
    const void* src = (z == 0) ? s0 : (z == 1) ? s1 : (z == 2) ? s2 :
                      (z == 3) ? s3 : (z == 4) ? s4 : (z == 5) ? s5 : s6;
    uint16_t* dh = (z == 0) ? gdst : tail + (size_t)(z - 1) * WSLOT;
    uint16_t* dl = dh + WMAT;
    int k0 = blockIdx.x * 64, n0 = blockIdx.y * 64;
    for (int t = threadIdx.x; t < 4096; t += 256) {
        int r = t >> 6, c = t & 63;
        tile[r][c] = loadf(src, (size_t)(k0 + r) * DD + n0 + c, isf);
    }
    __syncthreads();
    for (int base = 0; base < 4096; base += 512) {
        int t = base + threadIdx.x * 2;
        int r = t >> 6, c = t & 63;
        float va = tile[c][r], vb = tile[c + 1][r];
        uint16_t ha = f2b(va), hb = f2b(vb);
        size_t o = (size_t)(n0 + r) * DD + k0 + c;
        *(u16x2*)(dh + o) = (u16x2){ha, hb};
        *(u16x2*)(dl + o) = (u16x2){f2b(va - b2f(ha)), f2b(vb - b2f(hb))};
    }
}

// =============== MFMA GEMM: C[M,768] = A[M,768] @ BT^T, bf16 hi/lo ====
// Tile 256x128, BK=32, 8 waves (2M x 4N: wave = 128m x 32n), acc 64 f32.
// Double-buffered LDS (64KB), stage(t+1) issued before compute(t).
enum { EPI_NONE = 0, EPI_BIAS_RELU = 3, EPI_BIAS = 4 };

template<int EPI, int ISF>
__device__ __forceinline__ void mgemm_core(
    const uint16_t* __restrict__ Az, const uint16_t* __restrict__ Bh,
    const uint16_t* __restrict__ Bl, const void* bias,
    uint16_t* __restrict__ Cz, uint16_t* As, uint16_t* Bs, int m0, int n0) {
    const int tid = threadIdx.x, lane = tid & 63;
    const int wid = tid >> 6;
    const int wr = wid >> 2, wc = wid & 3;     // 2 M-halves x 4 N-quarters

    f32x4 acc[8][2];
    #pragma unroll
    for (int i = 0; i < 8; i++)
        #pragma unroll
        for (int j = 0; j < 2; j++) acc[i][j] = (f32x4){0.f, 0.f, 0.f, 0.f};

    // A staging: 1024 chunks over 512 thr x 2
    const int ar = tid >> 2;
    const int agl = (tid & 3) ^ ((ar >> 1) & 3);
    // B staging: 512 chunks hi (+512 lo)
    const int br = tid >> 2;
    const int bgl = agl;

    auto STAGE = [&](int buf, int k0) {
        #pragma unroll
        for (int rd = 0; rd < 2; rd++) {
            int r = rd * 128 + ar;
            gload16(Az + (size_t)(m0 + r) * DD + k0 + agl * 8,
                    As + buf * 8192 + (rd * 512 + tid) * 8);
        }
        gload16(Bh + (size_t)(n0 + br) * DD + k0 + bgl * 8, Bs + (buf * 2) * 4096 + tid * 8);
        if (ISF) gload16(Bl + (size_t)(n0 + br) * DD + k0 + bgl * 8, Bs + (buf * 2 + 1) * 4096 + tid * 8);
    };

    int offA[8], offB[2];
    #pragma unroll
    for (int i = 0; i < 8; i++) {
        int r = wr * 128 + i * 16 + (lane & 15);
        offA[i] = r * 32 + (((lane >> 4) ^ ((r >> 1) & 3)) << 3);
    }
    #pragma unroll
    for (int j = 0; j < 2; j++) {
        int r = wc * 32 + j * 16 + (lane & 15);
        offB[j] = r * 32 + (((lane >> 4) ^ ((r >> 1) & 3)) << 3);
    }

    STAGE(0, 0);
    __syncthreads();
    int cur = 0;
    for (int t = 0; t < 24; ++t) {
        if (t < 23) STAGE(cur ^ 1, (t + 1) * 32);
        const uint16_t* Ac = As + cur * 8192;
        const uint16_t* Bhc = Bs + (cur * 2) * 4096;
        bf16x8 af[8], b2[2], l2[2];
        #pragma unroll
        for (int i = 0; i < 8; i++) af[i] = *(const bf16x8*)(Ac + offA[i]);
        #pragma unroll
        for (int j = 0; j < 2; j++) {
            b2[j] = *(const bf16x8*)(Bhc + offB[j]);
            if (ISF) l2[j] = *(const bf16x8*)(Bhc + 4096 + offB[j]);
        }
        #pragma unroll
        for (int j = 0; j < 2; j++)
            #pragma unroll
            for (int i = 0; i < 8; i++)
                acc[i][j] = __builtin_amdgcn_mfma_f32_16x16x32_bf16(af[i], b2[j], acc[i][j], 0, 0, 0);
        if (ISF) {
            #pragma unroll
            for (int j = 0; j < 2; j++)
                #pragma unroll
                for (int i = 0; i < 8; i++)
                    acc[i][j] = __builtin_amdgcn_mfma_f32_16x16x32_bf16(af[i], l2[j], acc[i][j], 0, 0, 0);
        }
        __syncthreads();
        cur ^= 1;
    }
    // D layout: col = lane&15, row = (lane>>4)*4 + q
    #pragma unroll
    for (int i = 0; i < 8; i++) {
        #pragma unroll
        for (int j = 0; j < 2; j++) {
            int n = n0 + wc * 32 + j * 16 + (lane & 15);
            int mb = m0 + wr * 128 + i * 16 + ((lane >> 4) << 2);
            float bv = 0.f;
            if (EPI != EPI_NONE) bv = loadf(bias, n, ISF);
            #pragma unroll
            for (int q = 0; q < 4; q++) {
                float v = acc[i][j][q];
                if (EPI == EPI_BIAS_RELU) v = fmaxf(v + bv, 0.f);
                else if (EPI == EPI_BIAS) v = v + bv;
                Cz[(size_t)(mb + q) * DD + n] = f2b(v);
            }
        }
    }
}

template<int EPI>
__global__ __launch_bounds__(512, 4)
void k_mgemm(const uint16_t* __restrict__ A, uint32_t aZ,
             const uint16_t* __restrict__ BTh, uint32_t bZ,
             const void* bias0, const void* bias1, const void* bias2,
             uint16_t* __restrict__ C, uint32_t cZ,
             const int* __restrict__ flag) {
    __shared__ __align__(16) uint16_t As[2 * 8192];      // dbuf 256x32
    __shared__ __align__(16) uint16_t Bs[4 * 4096];      // dbuf x hi/lo 128x32
    const int isf = flag[0];
    const int z = blockIdx.z;
    const uint16_t* Az = A + (size_t)z * aZ;
    const uint16_t* Bh = BTh + (size_t)z * bZ;
    const uint16_t* Bl = Bh + WMAT;
    uint16_t* Cz = C + (size_t)z * cZ;
    const void* bias = (z == 0) ? bias0 : (z == 1) ? bias1 : bias2;
    const int m0 = blockIdx.y * 256, n0 = blockIdx.x * 128;
    if (isf) mgemm_core<EPI, 1>(Az, Bh, Bl, bias, Cz, As, Bs, m0, n0);
    else     mgemm_core<EPI, 0>(Az, Bh, Bl, bias, Cz, As, Bs, m0, n0);
}

// =============== MFMA fused GRU layer: 3-gate GEMM (hi/lo) + cell ====
// Tile 256m x (3 gates x 64n), BK=32, 8 waves (2M x 4N: wave = 128m x 16n/gate),
// acc 96 f32; double-buffered LDS 80KB; grid (12, 48).
template<int ISF>
__device__ __forceinline__ void grum_core(
    const uint16_t* __restrict__ X,
    const uint16_t* __restrict__ Wh, const uint16_t* __restrict__ Wl,
    const void* __restrict__ bih, const void* __restrict__ bhh,
    const float* __restrict__ giE, uint16_t* __restrict__ Xn,
    uint16_t* As, uint16_t* Bs, int m0, int n0) {
    const int tid = threadIdx.x, lane = tid & 63;
    const int wid = tid >> 6;
    const int wr = wid >> 2, wc = wid & 3;     // 2 M-halves x 4 N-quarters (16 cols/gate)

    f32x4 acc[3][8];
    #pragma unroll
    for (int gg = 0; gg < 3; gg++)
        #pragma unroll
        for (int i = 0; i < 8; i++) acc[gg][i] = (f32x4){0.f, 0.f, 0.f, 0.f};

    // A staging: 1024 chunks over 512 thr x 2
    const int ar = tid >> 2;
    const int agl = (tid & 3) ^ ((ar >> 1) & 3);
    // B staging: 1536 chunks (3 gates x 64 rows x 4 grp, hi then lo) over 512 x 3
    // chunk v = bt*512 + tid; h = v>=768; u = v - h*768; gg = u>>8; w = u&255

    auto STAGE = [&](int buf, int k0) {
        #pragma unroll
        for (int rd = 0; rd < 2; rd++) {
            int r = rd * 128 + ar;
            gload16(X + (size_t)(m0 + r) * DD + k0 + agl * 8,
                    As + buf * 8192 + (rd * 512 + tid) * 8);
        }
        #pragma unroll
        for (int bt = 0; bt < 3; bt++) {
            int v = bt * 512 + tid;
            int h = (v >= 768) ? 1 : 0;
            if (!ISF && h) continue;
            int u = v - h * 768;
            int gg = u >> 8, w = u & 255;
            int r = w >> 2;
            int gl = (w & 3) ^ ((r >> 1) & 3);
            const uint16_t* W = h ? Wl : Wh;
            gload16(W + (size_t)(gg * DD + n0 + r) * DD + k0 + gl * 8,
                    Bs + ((buf * 3 + gg) * 2 + h) * 2048 + w * 8);
        }
    };

    int offA[8], offB;
    #pragma unroll
    for (int i = 0; i < 8; i++) {
        int r = wr * 128 + i * 16 + (lane & 15);
        offA[i] = r * 32 + (((lane >> 4) ^ ((r >> 1) & 3)) << 3);
    }
    {
        int r = wc * 16 + (lane & 15);
        offB = r * 32 + (((lane >> 4) ^ ((r >> 1) & 3)) << 3);
    }

    STAGE(0, 0);
    __syncthreads();
    int cur = 0;
    for (int t = 0; t < 24; ++t) {
        if (t < 23) STAGE(cur ^ 1, (t + 1) * 32);
        const uint16_t* Ac = As + cur * 8192;
        bf16x8 af[8];
        #pragma unroll
        for (int i = 0; i < 8; i++) af[i] = *(const bf16x8*)(Ac + offA[i]);
        #pragma unroll
        for (int gg = 0; gg < 3; gg++) {
            const uint16_t* Bhc = Bs + ((cur * 3 + gg) * 2) * 2048;
            bf16x8 bh = *(const bf16x8*)(Bhc + offB);
            #pragma unroll
            for (int i = 0; i < 8; i++)
                acc[gg][i] = __builtin_amdgcn_mfma_f32_16x16x32_bf16(af[i], bh, acc[gg][i], 0, 0, 0);
            if (ISF) {
                bf16x8 bl = *(const bf16x8*)(Bhc + 2048 + offB);
                #pragma unroll
                for (int i = 0; i < 8; i++)
                    acc[gg][i] = __builtin_amdgcn_mfma_f32_16x16x32_bf16(af[i], bl, acc[gg][i], 0, 0, 0);
            }
        }
        __syncthreads();
        cur ^= 1;
    }
    // epilogue: full GRU cell pointwise (one n column-range per wave)
    {
        int n = n0 + wc * 16 + (lane & 15);
        float bh0 = loadf(bhh, n, ISF);
        float bh1 = loadf(bhh, DD + n, ISF);
        float bh2v = loadf(bhh, 2 * DD + n, ISF);
        float gE0 = giE[n], gE1 = giE[DD + n], gE2 = giE[2 * DD + n];
        float bi0 = loadf(bih, n, ISF);
        float bi1 = loadf(bih, DD + n, ISF);
        float bi2 = loadf(bih, 2 * DD + n, ISF);
        #pragma unroll
        for (int i = 0; i < 8; i++) {
            int mb = m0 + wr * 128 + i * 16 + ((lane >> 4) << 2);
            #pragma unroll
            for (int q = 0; q < 4; q++) {
                int m = mb + q;
                bool msg = (m < SS);
                float gr = msg ? gE0 : bi0;
                float gz = msg ? gE1 : bi1;
                float gn = msg ? gE2 : bi2;
                float rg = 1.f / (1.f + expf(-(acc[0][i][q] + bh0 + gr)));
                float zg = 1.f / (1.f + expf(-(acc[1][i][q] + bh1 + gz)));
                float hn = acc[2][i][q] + bh2v;
                float nn = tanhf(gn + rg * hn);
                float xo = b2f(X[(size_t)m * DD + n]);
                Xn[(size_t)m * DD + n] = f2b((1.f - zg) * nn + zg * xo);
            }
        }
    }
}

__global__ __launch_bounds__(512, 2)
void k_grum(const uint16_t* __restrict__ X,
            const uint16_t* __restrict__ Wh, const uint16_t* __restrict__ Wl,
            const void* __restrict__ bih, const void* __restrict__ bhh,
            const float* __restrict__ giE, uint16_t* __restrict__ Xn,
            const int* __restrict__ flag) {
    __shared__ __align__(16) uint16_t As[2 * 8192];      // dbuf 256x32 (32KB)
    __shared__ __align__(16) uint16_t Bs[12 * 2048];     // dbuf x 3 gates x hi/lo (48KB)
    const int n0 = blockIdx.x * 64, m0 = blockIdx.y * 256;
    if (flag[0]) grum_core<1>(X, Wh, Wl, bih, bhh, giE, Xn, As, Bs, m0, n0);
    else         grum_core<0>(X, Wh, Wl, bih, bhh, giE, Xn, As, Bs, m0, n0);
}

// ============================== driver ==============================
extern "C" void kernel_launch(void* const* d_in, const int* in_sizes, int n_in,
                              void* d_out, int out_size, void* d_ws, size_t ws_size,
                              hipStream_t stream) {
    float* OUTF = (float*)d_out;            // FINAL output: fp32
    uint16_t* OB = (uint16_t*)d_out;        // first 18.9MB of d_out as bf16 trunk/H scratch

    static const int expect[29] = {
        3145728,3145728,3145728,3145728, 589824,768, 1179648, 1769472,1769472, 2304,2304,
        589824,768,589824,768,768,768,
        589824,768,589824,768,768,768,
        589824,768,589824,768,768,768 };
    int bad = -1;
    if (n_in != 29) bad = 90;
    else { for (int i = 0; i < 29; i++) if (in_sizes[i] != expect[i]) { bad = i; break; } }
    if (bad < 0 && out_size != (int)TOTAL_ND) bad = 91;
    if (bad < 0 && ws_size < 33ull * 1024 * 1024) bad = 92;
    if (bad >= 0) {
        k_diag<<<1, 64, 0, stream>>>(OUTF, 10000.f + 100.f * (float)bad);
        return;
    }

    // ws layout (floats): small scratch | F128 hi/lo | W0 | WH | WT  (~30.8 MiB)
    float* fbase = (float*)d_ws;
    float* simb = fbase;                        // 16384
    float* mnmx = simb + 16384;                 // 2
    float* deg  = mnmx + 2;                     // 128
    float* dinv = deg + 128;                    // 128
    float* aggb = dinv + 128;                   // 98304
    float* svec = aggb + 98304;                 // 768
    float* mvec = svec + 768;                   // 768
    float* giE  = mvec + 768;                   // 2304
    int*   flag = (int*)(giE + 2304);           // 1
    uint16_t* F128h = (uint16_t*)(fbase + 118916);  // 98304 u16
    uint16_t* F128l = (uint16_t*)(fbase + 168068);  // 98304 u16
    uint16_t* W0 = (uint16_t*)(fbase + 217220);     // 9,437,184 u16
    uint16_t* WH = W0 + TOTAL_ND;                   // 3,145,728 u16 slots
    uint16_t* WT = WH + NBSD;                       // 3,145,728 u16 slots

    // head weights hi/lo live in the TAIL of d_out (last 13.5 MB; dead before LN)
    uint16_t* tailW = (uint16_t*)((char*)d_out + 23592960);  // 6 slots x WSLOT

    const void* hf = d_in[0];
    const void* hc = d_in[1];
    const void* hd = d_in[2];
    const void* hs = d_in[3];

    k_probe<<<1, 64, 0, stream>>>(hf, flag);

    // ---- all transpose-weight conversions batched (gcn_W -> WH, heads -> tail) ----
    k_cvtT7<<<dim3(12, 12, 7), 256, 0, stream>>>(
        d_in[4], d_in[11], d_in[13], d_in[17], d_in[19], d_in[23], d_in[25],
        WH, tailW, flag);

    // ---- GCN front-end ----
    k_build_all<<<3456, 256, 0, stream>>>(hc, hd, hs, W0, F128h, F128l, flag);
    k_simgemm<<<dim3(2, 2), 256, 0, stream>>>(F128h, F128l, simb);
    k_simpost<<<1, 256, 0, stream>>>(simb, mnmx);
    k_deg<<<SS, SS, 0, stream>>>(simb, mnmx, deg, dinv);
    k_mgemm<EPI_NONE><<<dim3(6, 48, 1), 512, 0, stream>>>(
        W0, 0, WH, 0, nullptr, nullptr, nullptr, OB, 0, flag);
    k_agg<<<dim3(SS, 3), 256, 0, stream>>>(simb, dinv, OB, aggb);
    k_gcn_combine<<<4608, 256, 0, stream>>>(OB, aggb, deg, d_in[5], flag);

    // ---- GatedGraphConv: whh hi->WH, lo->WT (gcn_W in WH now dead) ----
    k_cvt2<<<1728, 256, 0, stream>>>(d_in[8], WH, WT, 1769472, flag);

    k_colsum<<<12, 256, 0, stream>>>(OB, svec);
    k_matvec<<<3, 256, 0, stream>>>(svec, d_in[6], 0, mvec, flag);
    k_rowdot<<<2304, 256, 0, stream>>>(mvec, d_in[7], d_in[9], giE, flag);
    k_grum<<<dim3(12, 48), 512, 0, stream>>>(OB, WH, WT, d_in[9], d_in[10], giE, W0, flag);

    k_colsum<<<12, 256, 0, stream>>>(W0, svec);
    k_matvec<<<3, 256, 0, stream>>>(svec, d_in[6], (size_t)DD * DD, mvec, flag);
    k_rowdot<<<2304, 256, 0, stream>>>(mvec, d_in[7], d_in[9], giE, flag);
    k_grum<<<dim3(12, 48), 512, 0, stream>>>(W0, WH, WT, d_in[9], d_in[10], giE, OB, flag);

    // ---- y = hf + relu(x) for all 3 chunks (OB -> W0); OB then dead ----
    k_build_y<<<4608, 256, 0, stream>>>(hf, OB, W0, flag);

    // ---- heads batched over z: y(W0) -> H(OB) -> T(W0) -> LN(d_out) ----
    k_mgemm<EPI_BIAS_RELU><<<dim3(6, 16, 3), 512, 0, stream>>>(
        W0, NBSD, tailW, 2 * WSLOT, d_in[12], d_in[18], d_in[24], OB, NBSD, flag);
    k_mgemm<EPI_BIAS><<<dim3(6, 16, 3), 512, 0, stream>>>(
        OB, NBSD, tailW + WSLOT, 2 * WSLOT, d_in[14], d_in[20], d_in[26], W0, NBSD, flag);
    k_ln<<<NNODE, 256, 0, stream>>>(W0, d_in[15], d_in[16], d_in[21], d_in[22],
                                    d_in[27], d_in[28], OUTF, flag);
}

// Round 8
// 858.604 us; speedup vs baseline: 1.1696x; 1.1696x over previous
//
#include <hip/hip_runtime.h>
#include <cstdint>
#include <cstddef>

#define DD 768
#define SS 128
#define NNODE 12288            // 3*B*S
#define NBS 4096               // B*S
#define NBSD 3145728           // B*S*D (per-chunk elements)
#define TOTAL_ND 9437184ULL    // NNODE*DD == out_size (fp32 elements)
#define WMAT 589824            // 768*768
#define WSLOT 1179648          // hi+lo pair of one 768x768 matrix (u16 elems)

typedef __attribute__((ext_vector_type(4))) float f32x4;
typedef __attribute__((ext_vector_type(8))) short bf16x8;
typedef __attribute__((ext_vector_type(4))) uint16_t u16x4;
typedef __attribute__((ext_vector_type(2))) uint16_t u16x2;
typedef __attribute__((ext_vector_type(8))) uint16_t u16x8;
typedef __attribute__((ext_vector_type(2))) uint32_t u32x2;

__device__ __forceinline__ float b2f(uint16_t u) {
    union { uint32_t i; float f; } x; x.i = ((uint32_t)u) << 16; return x.f;
}
__device__ __forceinline__ uint16_t f2b(float f) {
    uint32_t x = __float_as_uint(f);
    return (uint16_t)((x + 0x7FFFu + ((x >> 16) & 1u)) >> 16);
}
__device__ __forceinline__ float loadf(const void* p, size_t i, int isf32) {
    return isf32 ? ((const float*)p)[i] : b2f(((const uint16_t*)p)[i]);
}
// feats[n][d] = src_{d%3}[n*256 + d/3]
__device__ __forceinline__ float featAt(const void* hc, const void* hd, const void* hs,
                                        int n, int d, int isf) {
    int w = d % 3;
    size_t u = (size_t)n * 256 + (size_t)(d / 3);
    const void* p = (w == 0) ? hc : (w == 1) ? hd : hs;
    return loadf(p, u, isf);
}
__device__ __forceinline__ uint32_t pk2(uint16_t a, uint16_t b) {
    return (uint32_t)a | ((uint32_t)b << 16);
}

// async 16B global->LDS (linear dest: wave-uniform base + lane*16)
__device__ __forceinline__ void gload16(const uint16_t* g, uint16_t* l) {
    __builtin_amdgcn_global_load_lds(
        (__attribute__((address_space(1))) uint32_t*)(uintptr_t)g,
        (__attribute__((address_space(3))) uint32_t*)l, 16, 0, 0);
}

// ---------- diag beacon ----------
__global__ void k_diag(float* out, float code) {
    if (threadIdx.x == 0 && blockIdx.x == 0) out[0] = code;
}

// ---------- dtype probe ----------
__global__ void k_probe(const void* hf, int* flag) {
    if (threadIdx.x == 0 && blockIdx.x == 0) {
        const uint32_t* w = (const uint32_t*)hf;
        int bad = 0;
        for (int k = 0; k < 64; k++) {
            uint16_t lo = (uint16_t)(w[k] & 0xFFFFu);
            int e = (lo >> 7) & 0xFF;
            if (e < 100 || e > 140) bad++;
        }
        flag[0] = (bad > 24) ? 1 : 0;
    }
}

// ---------- feats build + F128 hi/lo split (merged) ----------
__global__ __launch_bounds__(256) void k_build_all(
    const void* __restrict__ hc, const void* __restrict__ hd,
    const void* __restrict__ hs, uint16_t* __restrict__ feats,
    uint16_t* __restrict__ Fh, uint16_t* __restrict__ Fl,
    const int* __restrict__ flag) {
    int isf = flag[0];
    if (blockIdx.x < 3072) {
        int u = (blockIdx.x * 256 + threadIdx.x) * 4;
        float a[4], b[4], c[4];
        if (isf) {
            f32x4 va = *(const f32x4*)((const float*)hc + u);
            f32x4 vb = *(const f32x4*)((const float*)hd + u);
            f32x4 vc = *(const f32x4*)((const float*)hs + u);
            #pragma unroll
            for (int q = 0; q < 4; q++) { a[q] = va[q]; b[q] = vb[q]; c[q] = vc[q]; }
        } else {
            u16x4 va = *(const u16x4*)((const uint16_t*)hc + u);
            u16x4 vb = *(const u16x4*)((const uint16_t*)hd + u);
            u16x4 vc = *(const u16x4*)((const uint16_t*)hs + u);
            #pragma unroll
            for (int q = 0; q < 4; q++) { a[q] = b2f(va[q]); b[q] = b2f(vb[q]); c[q] = b2f(vc[q]); }
        }
        uint16_t o[12];
        #pragma unroll
        for (int q = 0; q < 4; q++) {
            o[3 * q] = f2b(a[q]); o[3 * q + 1] = f2b(b[q]); o[3 * q + 2] = f2b(c[q]);
        }
        u32x2 w0 = {pk2(o[0], o[1]), pk2(o[2], o[3])};
        u32x2 w1 = {pk2(o[4], o[5]), pk2(o[6], o[7])};
        u32x2 w2 = {pk2(o[8], o[9]), pk2(o[10], o[11])};
        *(u32x2*)(feats + (size_t)3 * u) = w0;
        *(u32x2*)(feats + (size_t)3 * u + 4) = w1;
        *(u32x2*)(feats + (size_t)3 * u + 8) = w2;
    } else {
        int t = (blockIdx.x - 3072) * 256 + threadIdx.x;   // 384 blocks -> 98304
        int n = t / DD, d = t - n * DD;
        float v = featAt(hc, hd, hs, n, d, isf);
        uint16_t h = f2b(v);
        Fh[t] = h;
        Fl[t] = f2b(v - b2f(h));
    }
}

// ---------- G = F F^T via MFMA hi/lo (drops ll term, ~1e-5 rel err) ----------
__global__ __launch_bounds__(256)
void k_simgemm(const uint16_t* __restrict__ Fh, const uint16_t* __restrict__ Fl,
               float* __restrict__ G) {
    __shared__ __align__(16) uint16_t Ah[64 * 32], Al[64 * 32], Bh_[64 * 32], Bl_[64 * 32];
    const int tid = threadIdx.x, lane = tid & 63, wid = tid >> 6;
    const int wr = wid >> 1, wc = wid & 1;
    const int m0 = blockIdx.y * 64, n0 = blockIdx.x * 64;
    f32x4 acc[2][2];
    #pragma unroll
    for (int i = 0; i < 2; i++)
        #pragma unroll
        for (int j = 0; j < 2; j++) acc[i][j] = (f32x4){0.f, 0.f, 0.f, 0.f};
    const int sr = tid >> 2, sg = tid & 3;
    const int sgl = sg ^ ((sr >> 1) & 3);
    const int dofs = wid * 64 * 8;
    for (int k0 = 0; k0 < DD; k0 += 32) {
        gload16(Fh + (size_t)(m0 + sr) * DD + k0 + sgl * 8, Ah + dofs);
        gload16(Fl + (size_t)(m0 + sr) * DD + k0 + sgl * 8, Al + dofs);
        gload16(Fh + (size_t)(n0 + sr) * DD + k0 + sgl * 8, Bh_ + dofs);
        gload16(Fl + (size_t)(n0 + sr) * DD + k0 + sgl * 8, Bl_ + dofs);
        __syncthreads();
        bf16x8 ah[2], al[2], bh2[2], bl2[2];
        #pragma unroll
        for (int i = 0; i < 2; i++) {
            int r = wr * 32 + i * 16 + (lane & 15);
            int g = (lane >> 4) ^ ((r >> 1) & 3);
            ah[i] = *(const bf16x8*)(Ah + r * 32 + g * 8);
            al[i] = *(const bf16x8*)(Al + r * 32 + g * 8);
        }
        #pragma unroll
        for (int j = 0; j < 2; j++) {
            int r = wc * 32 + j * 16 + (lane & 15);
            int g = (lane >> 4) ^ ((r >> 1) & 3);
            bh2[j] = *(const bf16x8*)(Bh_ + r * 32 + g * 8);
            bl2[j] = *(const bf16x8*)(Bl_ + r * 32 + g * 8);
        }
        #pragma unroll
        for (int i = 0; i < 2; i++)
            #pragma unroll
            for (int j = 0; j < 2; j++)
                acc[i][j] = __builtin_amdgcn_mfma_f32_16x16x32_bf16(ah[i], bh2[j], acc[i][j], 0, 0, 0);
        #pragma unroll
        for (int i = 0; i < 2; i++)
            #pragma unroll
            for (int j = 0; j < 2; j++)
                acc[i][j] = __builtin_amdgcn_mfma_f32_16x16x32_bf16(ah[i], bl2[j], acc[i][j], 0, 0, 0);
        #pragma unroll
        for (int i = 0; i < 2; i++)
            #pragma unroll
            for (int j = 0; j < 2; j++)
                acc[i][j] = __builtin_amdgcn_mfma_f32_16x16x32_bf16(al[i], bh2[j], acc[i][j], 0, 0, 0);
        __syncthreads();
    }
    #pragma unroll
    for (int i = 0; i < 2; i++)
        #pragma unroll
        for (int j = 0; j < 2; j++) {
            int n = n0 + wc * 32 + j * 16 + (lane & 15);
            int mb = m0 + wr * 32 + i * 16 + ((lane >> 4) << 2);
            #pragma unroll
            for (int q = 0; q < 4; q++)
                G[(size_t)(mb + q) * SS + n] = acc[i][j][q];
        }
}

// ---------- sim post: nrm from diag -> cos normalize (in place) -> minmax ----------
__global__ __launch_bounds__(256) void k_simpost(float* __restrict__ simb,
                                                 float* __restrict__ mnmx) {
    int tid = threadIdx.x;
    __shared__ float nrmS[SS];
    if (tid < SS) nrmS[tid] = fmaxf(sqrtf(simb[(size_t)tid * SS + tid]), 1e-8f);
    __syncthreads();
    float mn = 3.4e38f, mx = -3.4e38f;
    for (int e = tid; e < SS * SS; e += 256) {
        int i = e >> 7, j = e & 127;
        float v = simb[e] / (nrmS[i] * nrmS[j]);
        simb[e] = v;
        mn = fminf(mn, v); mx = fmaxf(mx, v);
    }
    __shared__ float rmn[256], rmx[256];
    rmn[tid] = mn; rmx[tid] = mx; __syncthreads();
    for (int o = 128; o > 0; o >>= 1) {
        if (tid < o) { rmn[tid] = fminf(rmn[tid], rmn[tid + o]); rmx[tid] = fmaxf(rmx[tid], rmx[tid + o]); }
        __syncthreads();
    }
    if (tid == 0) { mnmx[0] = rmn[0]; mnmx[1] = rmx[0]; }
}

// ---------- min-max normalize sims in place, deg/dinv ----------
__global__ __launch_bounds__(128) void k_deg(float* __restrict__ simb,
                                             const float* __restrict__ mnmx,
                                             float* __restrict__ deg,
                                             float* __restrict__ dinv) {
    int j = blockIdx.x, i = threadIdx.x;
    float mn = mnmx[0], inv = 1.f / (mnmx[1] - mnmx[0]);
    float s = (simb[i * SS + j] - mn) * inv;
    simb[i * SS + j] = s;
    __shared__ float red[128];
    red[i] = s; __syncthreads();
    for (int o = 64; o > 0; o >>= 1) { if (i < o) red[i] += red[i + o]; __syncthreads(); }
    if (i == 0) { float d = red[0] + 1.f; deg[j] = d; dinv[j] = rsqrtf(d); }
}

// ---------- GCN neighbor aggregate (j<128), grid (SS,3) ----------
__global__ __launch_bounds__(256) void k_agg(const float* __restrict__ simb,
                                             const float* __restrict__ dinv,
                                             const uint16_t* __restrict__ xw,
                                             float* __restrict__ aggb) {
    int j = blockIdx.x;
    int d = blockIdx.y * 256 + threadIdx.x;
    __shared__ float w[SS];
    if (threadIdx.x < SS) w[threadIdx.x] = dinv[threadIdx.x] * simb[threadIdx.x * SS + j] * dinv[j];
    __syncthreads();
    float s = 0.f;
    #pragma unroll 8
    for (int i = 0; i < SS; i++) s += w[i] * b2f(xw[(size_t)i * DD + d]);
    aggb[(size_t)j * DD + d] = s;
}

// ---------- GCN combine in place (vec x8, bf16 state) ----------
__global__ __launch_bounds__(256) void k_gcn_combine(uint16_t* __restrict__ xw,
                                                     const float* __restrict__ aggb,
                                                     const float* __restrict__ deg,
                                                     const void* __restrict__ gcnb,
                                                     const int* __restrict__ flag) {
    uint32_t t = (blockIdx.x * 256 + threadIdx.x) * 8u;   // 4608 blocks, exact
    int isf = flag[0];
    uint32_t n = t / 768u;
    uint32_t d0 = t - n * 768u;
    u16x8 xv = *(const u16x8*)(xw + t);
    float v[8];
    #pragma unroll
    for (int q = 0; q < 8; q++) v[q] = b2f(xv[q]);
    if (n < SS) {
        f32x4 a0 = *(const f32x4*)(aggb + t);
        f32x4 a1 = *(const f32x4*)(aggb + t + 4);
        float dg = deg[n];
        #pragma unroll
        for (int q = 0; q < 4; q++) { v[q] = v[q] / dg + a0[q]; v[q + 4] = v[q + 4] / dg + a1[q]; }
    }
    float bb[8];
    if (isf) {
        f32x4 b0 = *(const f32x4*)((const float*)gcnb + d0);
        f32x4 b1 = *(const f32x4*)((const float*)gcnb + d0 + 4);
        #pragma unroll
        for (int q = 0; q < 4; q++) { bb[q] = b0[q]; bb[q + 4] = b1[q]; }
    } else {
        u16x8 b8 = *(const u16x8*)((const uint16_t*)gcnb + d0);
        #pragma unroll
        for (int q = 0; q < 8; q++) bb[q] = b2f(b8[q]);
    }
    u16x8 ov;
    #pragma unroll
    for (int q = 0; q < 8; q++) ov[q] = f2b(fmaxf(v[q] + bb[q], 0.f));
    *(u16x8*)(xw + t) = ov;
}

// ---------- colsum over first 128 rows (12 blocks, 4-way row split) ----------
__global__ __launch_bounds__(256) void k_colsum(const uint16_t* __restrict__ x,
                                                float* __restrict__ svec) {
    int d = blockIdx.x * 64 + (threadIdx.x & 63);
    int part = threadIdx.x >> 6;
    float s = 0.f;
    for (int i = part * 32; i < part * 32 + 32; i++) s += b2f(x[(size_t)i * DD + d]);
    __shared__ float red[256];
    red[threadIdx.x] = s; __syncthreads();
    if (part == 0)
        svec[d] = red[threadIdx.x] + red[threadIdx.x + 64] +
                  red[threadIdx.x + 128] + red[threadIdx.x + 192];
}

// ---------- mvec = svec @ ggc_W[l] ----------
__global__ __launch_bounds__(256) void k_matvec(const float* __restrict__ svec,
                                                const void* __restrict__ Wg, size_t ofs,
                                                float* __restrict__ mvec,
                                                const int* __restrict__ flag) {
    int k = blockIdx.x * 256 + threadIdx.x;
    int isf = flag[0];
    if (k < DD) {
        float s = 0.f;
        for (int d = 0; d < DD; d++) s += svec[d] * loadf(Wg, ofs + (size_t)d * DD + k, isf);
        mvec[k] = s;
    }
}

// ---------- giE = mvec @ wih.T + bih ----------
__global__ __launch_bounds__(256) void k_rowdot(const float* __restrict__ mvec,
                                                const void* __restrict__ wih,
                                                const void* __restrict__ bih,
                                                float* __restrict__ giE,
                                                const int* __restrict__ flag) {
    int rr = blockIdx.x, tid = threadIdx.x;
    int isf = flag[0];
    float s = 0.f;
    for (int k = tid; k < DD; k += 256) s += mvec[k] * loadf(wih, (size_t)rr * DD + k, isf);
    __shared__ float red[256];
    red[tid] = s; __syncthreads();
    for (int o = 128; o > 0; o >>= 1) { if (tid < o) red[tid] += red[tid + o]; __syncthreads(); }
    if (tid == 0) giE[rr] = red[0] + loadf(bih, rr, isf);
}

// ---------- y = h_feature + relu(x_g), batched all 3 chunks, vec x8 ----------
__global__ __launch_bounds__(256) void k_build_y(const void* __restrict__ hf,
                                                 const uint16_t* __restrict__ xg,
                                                 uint16_t* __restrict__ y,
                                                 const int* __restrict__ flag) {
    uint32_t t = (blockIdx.x * 256 + threadIdx.x) * 8u;   // 4608 blocks, exact TOTAL_ND
    int isf = flag[0];
    uint32_t u = t;
    if (u >= 2u * NBSD) u -= 2u * NBSD; else if (u >= NBSD) u -= NBSD;
    u16x8 xv = *(const u16x8*)(xg + t);
    float h[8];
    if (isf) {
        f32x4 h0 = *(const f32x4*)((const float*)hf + u);
        f32x4 h1 = *(const f32x4*)((const float*)hf + u + 4);
        #pragma unroll
        for (int q = 0; q < 4; q++) { h[q] = h0[q]; h[q + 4] = h1[q]; }
    } else {
        u16x8 h8 = *(const u16x8*)((const uint16_t*)hf + u);
        #pragma unroll
        for (int q = 0; q < 8; q++) h[q] = b2f(h8[q]);
    }
    u16x8 ov;
    #pragma unroll
    for (int q = 0; q < 8; q++) ov[q] = f2b(h[q] + fmaxf(b2f(xv[q]), 0.f));
    *(u16x8*)(y + t) = ov;
}

// ---------- LayerNorm (batched: 12288 rows, per-g weight select) ----------
__global__ __launch_bounds__(256) void k_ln(const uint16_t* __restrict__ tin,
                                            const void* g0, const void* b0,
                                            const void* g1, const void* b1,
                                            const void* g2, const void* b2,
                                            float* __restrict__ out,
                                            const int* __restrict__ flag) {
    int m = blockIdx.x, tid = threadIdx.x;
    int isf = flag[0];
    int gs = m >> 12;
    const void* gw = (gs == 0) ? g0 : (gs == 1) ? g1 : g2;
    const void* bw = (gs == 0) ? b0 : (gs == 1) ? b1 : b2;
    float v0 = b2f(tin[(size_t)m * DD + tid]);
    float v1 = b2f(tin[(size_t)m * DD + tid + 256]);
    float v2 = b2f(tin[(size_t)m * DD + tid + 512]);
    __shared__ float red[256];
    red[tid] = v0 + v1 + v2; __syncthreads();
    for (int o = 128; o > 0; o >>= 1) { if (tid < o) red[tid] += red[tid + o]; __syncthreads(); }
    float mu = red[0] * (1.f / 768.f);
    __syncthreads();
    float d0 = v0 - mu, d1 = v1 - mu, d2 = v2 - mu;
    red[tid] = d0 * d0 + d1 * d1 + d2 * d2; __syncthreads();
    for (int o = 128; o > 0; o >>= 1) { if (tid < o) red[tid] += red[tid + o]; __syncthreads(); }
    float rstd = rsqrtf(red[0] * (1.f / 768.f) + 1e-5f);
    out[(size_t)m * DD + tid]       = d0 * rstd * loadf(gw, tid, isf)       + loadf(bw, tid, isf);
    out[(size_t)m * DD + tid + 256] = d1 * rstd * loadf(gw, tid + 256, isf) + loadf(bw, tid + 256, isf);
    out[(size_t)m * DD + tid + 512] = d2 * rstd * loadf(gw, tid + 512, isf) + loadf(bw, tid + 512, isf);
}

// ---------- weight convert: hi-only bf16, elementwise vec x4 (whh) ----------
__global__ __launch_bounds__(256) void k_cvt1(const void* __restrict__ src,
                                              uint16_t* __restrict__ dh, int n,
                                              const int* __restrict__ flag) {
    int t = (blockIdx.x * 256 + threadIdx.x) * 4;   // exact cover
    int isf = flag[0];
    u16x4 hh;
    if (isf) {
        f32x4 s = *(const f32x4*)((const float*)src + t);
        #pragma unroll
        for (int q = 0; q < 4; q++) hh[q] = f2b(s[q]);
    } else {
        hh = *(const u16x4*)((const uint16_t*)src + t);
    }
    *(u16x4*)(dh + t) = hh;
}

// ---------- weight convert: transpose + hi/lo split, 7 matrices batched ----------
__global__ __launch_bounds__(256) void k_cvtT7(const void* s0, const void* s1,
                                               const void* s2, const void* s3,
                                               const void* s4, const void* s5,
                                               const void* s6,
                                               uint16_t* __restrict__ gdst,
                                               uint16_t* __restrict__ tail,
                                               const int* __restrict__ flag) {
    __shared__ float tile[64][65];
    int isf = flag[0];
    int z = blockIdx.z;
    const void* src = (z == 0) ? s0 : (z == 1) ? s1 : (z == 2) ? s2 :
                      (z == 3) ? s3 : (z == 4) ? s4 : (z == 5) ? s5 : s6;
    uint16_t* dh = (z == 0) ? gdst : tail + (size_t)(z - 1) * WSLOT;
    uint16_t* dl = dh + WMAT;
    int k0 = blockIdx.x * 64, n0 = blockIdx.y * 64;
    for (int t = threadIdx.x; t < 4096; t += 256) {
        int r = t >> 6, c = t & 63;
        tile[r][c] = loadf(src, (size_t)(k0 + r) * DD + n0 + c, isf);
    }
    __syncthreads();
    for (int base = 0; base < 4096; base += 512) {
        int t = base + threadIdx.x * 2;
        int r = t >> 6, c = t & 63;
        float va = tile[c][r], vb = tile[c + 1][r];
        uint16_t ha = f2b(va), hb = f2b(vb);
        size_t o = (size_t)(n0 + r) * DD + k0 + c;
        *(u16x2*)(dh + o) = (u16x2){ha, hb};
        *(u16x2*)(dl + o) = (u16x2){f2b(va - b2f(ha)), f2b(vb - b2f(hb))};
    }
}

// =============== MFMA GEMM: C[M,768] = A[M,768] @ BT^T, bf16 hi/lo combined ====
// 128x128 tile, BK=32, 8 waves (512 thr): per-wave 32x64, acc=32 floats.
// Single-buffer m97-style loop; occupancy (not ILP) hides staging latency.
enum { EPI_NONE = 0, EPI_BIAS_RELU = 3, EPI_BIAS = 4 };

template<int EPI, int ISF>
__device__ __forceinline__ void mgemm_core(
    const uint16_t* __restrict__ Az, const uint16_t* __restrict__ Bh,
    const uint16_t* __restrict__ Bl, const void* bias,
    uint16_t* __restrict__ Cz, uint16_t* As, uint16_t* Bs, int m0, int n0) {
    const int tid = threadIdx.x, lane = tid & 63;
    const int wid = tid >> 6;                  // 0..7
    const int wr = wid >> 1, wc = wid & 1;     // 4 M-quads x 2 N-halves

    f32x4 acc[2][4];
    #pragma unroll
    for (int i = 0; i < 2; i++)
        #pragma unroll
        for (int j = 0; j < 4; j++) acc[i][j] = (f32x4){0.f, 0.f, 0.f, 0.f};

    // staging indices: 512 chunks of 16B cover a 128x32 tile (4 groups/row)
    const int scr = tid >> 2;                              // row 0..127
    const int sgl = (tid & 3) ^ ((scr >> 1) & 3);          // swizzled group
    const int sdst = tid * 8;                              // wave-linear dest

    int offA[2], offB[4];
    #pragma unroll
    for (int i = 0; i < 2; i++) {
        int r = wr * 32 + i * 16 + (lane & 15);
        offA[i] = r * 32 + (((lane >> 4) ^ ((r >> 1) & 3)) << 3);
    }
    #pragma unroll
    for (int j = 0; j < 4; j++) {
        int r = wc * 64 + j * 16 + (lane & 15);
        offB[j] = r * 32 + (((lane >> 4) ^ ((r >> 1) & 3)) << 3);
    }

    for (int k0 = 0; k0 < DD; k0 += 32) {
        gload16(Az + (size_t)(m0 + scr) * DD + k0 + sgl * 8, As + sdst);
        gload16(Bh + (size_t)(n0 + scr) * DD + k0 + sgl * 8, Bs + sdst);
        if (ISF) gload16(Bl + (size_t)(n0 + scr) * DD + k0 + sgl * 8, Bs + 4096 + sdst);
        __syncthreads();
        bf16x8 af[2], b4[4], l4[4];
        #pragma unroll
        for (int i = 0; i < 2; i++) af[i] = *(const bf16x8*)(As + offA[i]);
        #pragma unroll
        for (int j = 0; j < 4; j++) {
            b4[j] = *(const bf16x8*)(Bs + offB[j]);
            if (ISF) l4[j] = *(const bf16x8*)(Bs + 4096 + offB[j]);
        }
        #pragma unroll
        for (int i = 0; i < 2; i++)
            #pragma unroll
            for (int j = 0; j < 4; j++)
                acc[i][j] = __builtin_amdgcn_mfma_f32_16x16x32_bf16(af[i], b4[j], acc[i][j], 0, 0, 0);
        if (ISF) {
            #pragma unroll
            for (int i = 0; i < 2; i++)
                #pragma unroll
                for (int j = 0; j < 4; j++)
                    acc[i][j] = __builtin_amdgcn_mfma_f32_16x16x32_bf16(af[i], l4[j], acc[i][j], 0, 0, 0);
        }
        __syncthreads();
    }
    // D layout: col = lane&15, row = (lane>>4)*4 + q
    #pragma unroll
    for (int i = 0; i < 2; i++) {
        #pragma unroll
        for (int j = 0; j < 4; j++) {
            int n = n0 + wc * 64 + j * 16 + (lane & 15);
            int mb = m0 + wr * 32 + i * 16 + ((lane >> 4) << 2);
            float bv = 0.f;
            if (EPI != EPI_NONE) bv = loadf(bias, n, ISF);
            #pragma unroll
            for (int q = 0; q < 4; q++) {
                float v = acc[i][j][q];
                if (EPI == EPI_BIAS_RELU) v = fmaxf(v + bv, 0.f);
                else if (EPI == EPI_BIAS) v = v + bv;
                Cz[(size_t)(mb + q) * DD + n] = f2b(v);
            }
        }
    }
}

template<int EPI>
__global__ __launch_bounds__(512, 4)
void k_mgemm(const uint16_t* __restrict__ A, uint32_t aZ,
             const uint16_t* __restrict__ BTh, uint32_t bZ,
             const void* bias0, const void* bias1, const void* bias2,
             uint16_t* __restrict__ C, uint32_t cZ,
             const int* __restrict__ flag) {
    __shared__ __align__(16) uint16_t As[4096];      // 128x32
    __shared__ __align__(16) uint16_t Bs[2 * 4096];  // hi/lo
    const int isf = flag[0];
    const int z = blockIdx.z;
    const uint16_t* Az = A + (size_t)z * aZ;
    const uint16_t* Bh = BTh + (size_t)z * bZ;
    const uint16_t* Bl = Bh + WMAT;
    uint16_t* Cz = C + (size_t)z * cZ;
    const void* bias = (z == 0) ? bias0 : (z == 1) ? bias1 : bias2;
    const int m0 = blockIdx.y * 128, n0 = blockIdx.x * 128;
    if (isf) mgemm_core<EPI, 1>(Az, Bh, Bl, bias, Cz, As, Bs, m0, n0);
    else     mgemm_core<EPI, 0>(Az, Bh, Bl, bias, Cz, As, Bs, m0, n0);
}

// =============== MFMA fused GRU layer: 3-gate GEMM (whh hi-only) + cell ====
// Tile M=128 x (3 gates x 64), 8 waves (512 thr): per-wave 32M x 32N/gate,
// acc = 48 floats. Single-buffer loop; grid (12, 96). whh bf16 hi only:
// B-lo error ~1e-3 abs on gate pre-activations, << trunk bf16 error floor.
template<int ISF>
__device__ __forceinline__ void grum_core(
    const uint16_t* __restrict__ X,
    const uint16_t* __restrict__ Wh,
    const void* __restrict__ bih, const void* __restrict__ bhh,
    const float* __restrict__ giE, uint16_t* __restrict__ Xn,
    uint16_t* As, uint16_t* Bs, int m0, int n0) {
    const int tid = threadIdx.x, lane = tid & 63;
    const int wid = tid >> 6;                  // 0..7
    const int wr = wid >> 1, wc = wid & 1;     // 4 M-quads x 2 N-halves

    f32x4 acc[3][2][2];
    #pragma unroll
    for (int gg = 0; gg < 3; gg++)
        #pragma unroll
        for (int i = 0; i < 2; i++)
            #pragma unroll
            for (int j = 0; j < 2; j++) acc[gg][i][j] = (f32x4){0.f, 0.f, 0.f, 0.f};

    // A staging: 512 chunks cover 128x32
    const int acr = tid >> 2;
    const int agl = (tid & 3) ^ ((acr >> 1) & 3);
    // B staging: threads 0..255 stage 3 gates (hi only), 256 chunks per gate
    const int bc = tid & 255;
    const int bcr = bc >> 2;
    const int bgl = (bc & 3) ^ ((bcr >> 1) & 3);

    int offA[2], offB[2];
    #pragma unroll
    for (int i = 0; i < 2; i++) {
        int r = wr * 32 + i * 16 + (lane & 15);
        offA[i] = r * 32 + (((lane >> 4) ^ ((r >> 1) & 3)) << 3);
    }
    #pragma unroll
    for (int j = 0; j < 2; j++) {
        int r = wc * 32 + j * 16 + (lane & 15);
        offB[j] = r * 32 + (((lane >> 4) ^ ((r >> 1) & 3)) << 3);
    }

    for (int k0 = 0; k0 < DD; k0 += 32) {
        gload16(X + (size_t)(m0 + acr) * DD + k0 + agl * 8, As + tid * 8);
        if (tid < 256) {
            #pragma unroll
            for (int gg = 0; gg < 3; gg++)
                gload16(Wh + (size_t)(gg * DD + n0 + bcr) * DD + k0 + bgl * 8,
                        Bs + gg * 2048 + bc * 8);
        }
        __syncthreads();
        bf16x8 af[2];
        #pragma unroll
        for (int i = 0; i < 2; i++) af[i] = *(const bf16x8*)(As + offA[i]);
        #pragma unroll
        for (int gg = 0; gg < 3; gg++) {
            const uint16_t* Bhc = Bs + gg * 2048;
            bf16x8 bh2[2];
            #pragma unroll
            for (int j = 0; j < 2; j++) bh2[j] = *(const bf16x8*)(Bhc + offB[j]);
            #pragma unroll
            for (int j = 0; j < 2; j++)
                #pragma unroll
                for (int i = 0; i < 2; i++)
                    acc[gg][i][j] = __builtin_amdgcn_mfma_f32_16x16x32_bf16(af[i], bh2[j], acc[gg][i][j], 0, 0, 0);
        }
        __syncthreads();
    }
    // epilogue: full GRU cell pointwise
    #pragma unroll
    for (int j = 0; j < 2; j++) {
        int n = n0 + wc * 32 + j * 16 + (lane & 15);
        float bh0 = loadf(bhh, n, ISF);
        float bh1 = loadf(bhh, DD + n, ISF);
        float bh2v = loadf(bhh, 2 * DD + n, ISF);
        float gE0 = giE[n], gE1 = giE[DD + n], gE2 = giE[2 * DD + n];
        float bi0 = loadf(bih, n, ISF);
        float bi1 = loadf(bih, DD + n, ISF);
        float bi2 = loadf(bih, 2 * DD + n, ISF);
        #pragma unroll
        for (int i = 0; i < 2; i++) {
            int mb = m0 + wr * 32 + i * 16 + ((lane >> 4) << 2);
            #pragma unroll
            for (int q = 0; q < 4; q++) {
                int m = mb + q;
                bool msg = (m < SS);
                float gr = msg ? gE0 : bi0;
                float gz = msg ? gE1 : bi1;
                float gn = msg ? gE2 : bi2;
                float rg = 1.f / (1.f + expf(-(acc[0][i][j][q] + bh0 + gr)));
                float zg = 1.f / (1.f + expf(-(acc[1][i][j][q] + bh1 + gz)));
                float hn = acc[2][i][j][q] + bh2v;
                float nn = tanhf(gn + rg * hn);
                float xo = b2f(X[(size_t)m * DD + n]);
                Xn[(size_t)m * DD + n] = f2b((1.f - zg) * nn + zg * xo);
            }
        }
    }
}

__global__ __launch_bounds__(512, 4)
void k_grum(const uint16_t* __restrict__ X,
            const uint16_t* __restrict__ Wh,
            const void* __restrict__ bih, const void* __restrict__ bhh,
            const float* __restrict__ giE, uint16_t* __restrict__ Xn,
            const int* __restrict__ flag) {
    __shared__ __align__(16) uint16_t As[4096];          // 128x32 (8KB)
    __shared__ __align__(16) uint16_t Bs[3 * 2048];      // 3 gates x 64x32 hi (12KB)
    const int n0 = blockIdx.x * 64, m0 = blockIdx.y * 128;
    if (flag[0]) grum_core<1>(X, Wh, bih, bhh, giE, Xn, As, Bs, m0, n0);
    else         grum_core<0>(X, Wh, bih, bhh, giE, Xn, As, Bs, m0, n0);
}

// ============================== driver ==============================
extern "C" void kernel_launch(void* const* d_in, const int* in_sizes, int n_in,
                              void* d_out, int out_size, void* d_ws, size_t ws_size,
                              hipStream_t stream) {
    float* OUTF = (float*)d_out;            // FINAL output: fp32
    uint16_t* OB = (uint16_t*)d_out;        // first 18.9MB of d_out as bf16 trunk/H scratch

    static const int expect[29] = {
        3145728,3145728,3145728,3145728, 589824,768, 1179648, 1769472,1769472, 2304,2304,
        589824,768,589824,768,768,768,
        589824,768,589824,768,768,768,
        589824,768,589824,768,768,768 };
    int bad = -1;
    if (n_in != 29) bad = 90;
    else { for (int i = 0; i < 29; i++) if (in_sizes[i] != expect[i]) { bad = i; break; } }
    if (bad < 0 && out_size != (int)TOTAL_ND) bad = 91;
    if (bad < 0 && ws_size < 33ull * 1024 * 1024) bad = 92;
    if (bad >= 0) {
        k_diag<<<1, 64, 0, stream>>>(OUTF, 10000.f + 100.f * (float)bad);
        return;
    }

    // ws layout (floats): small scratch | F128 hi/lo | W0 | WH | WT  (~30.8 MiB)
    float* fbase = (float*)d_ws;
    float* simb = fbase;                        // 16384
    float* mnmx = simb + 16384;                 // 2
    float* deg  = mnmx + 2;                     // 128
    float* dinv = deg + 128;                    // 128
    float* aggb = dinv + 128;                   // 98304
    float* svec = aggb + 98304;                 // 768
    float* mvec = svec + 768;                   // 768
    float* giE  = mvec + 768;                   // 2304
    int*   flag = (int*)(giE + 2304);           // 1
    uint16_t* F128h = (uint16_t*)(fbase + 118916);  // 98304 u16
    uint16_t* F128l = (uint16_t*)(fbase + 168068);  // 98304 u16
    uint16_t* W0 = (uint16_t*)(fbase + 217220);     // 9,437,184 u16
    uint16_t* WH = W0 + TOTAL_ND;                   // 3,145,728 u16 slots
    uint16_t* WT = WH + NBSD;                       // 3,145,728 u16 slots (spare)

    // head weights hi/lo live in the TAIL of d_out (last 13.5 MB; dead before LN)
    uint16_t* tailW = (uint16_t*)((char*)d_out + 23592960);  // 6 slots x WSLOT

    const void* hf = d_in[0];
    const void* hc = d_in[1];
    const void* hd = d_in[2];
    const void* hs = d_in[3];

    k_probe<<<1, 64, 0, stream>>>(hf, flag);

    // ---- all transpose-weight conversions batched (gcn_W -> WH, heads -> tail) ----
    k_cvtT7<<<dim3(12, 12, 7), 256, 0, stream>>>(
        d_in[4], d_in[11], d_in[13], d_in[17], d_in[19], d_in[23], d_in[25],
        WH, tailW, flag);

    // ---- GCN front-end ----
    k_build_all<<<3456, 256, 0, stream>>>(hc, hd, hs, W0, F128h, F128l, flag);
    k_simgemm<<<dim3(2, 2), 256, 0, stream>>>(F128h, F128l, simb);
    k_simpost<<<1, 256, 0, stream>>>(simb, mnmx);
    k_deg<<<SS, SS, 0, stream>>>(simb, mnmx, deg, dinv);
    k_mgemm<EPI_NONE><<<dim3(6, 96, 1), 512, 0, stream>>>(
        W0, 0, WH, 0, nullptr, nullptr, nullptr, OB, 0, flag);
    k_agg<<<dim3(SS, 3), 256, 0, stream>>>(simb, dinv, OB, aggb);
    k_gcn_combine<<<4608, 256, 0, stream>>>(OB, aggb, deg, d_in[5], flag);

    // ---- GatedGraphConv: whh -> WH bf16 hi only (gcn_W in WH now dead) ----
    k_cvt1<<<1728, 256, 0, stream>>>(d_in[8], WH, 1769472, flag);

    k_colsum<<<12, 256, 0, stream>>>(OB, svec);
    k_matvec<<<3, 256, 0, stream>>>(svec, d_in[6], 0, mvec, flag);
    k_rowdot<<<2304, 256, 0, stream>>>(mvec, d_in[7], d_in[9], giE, flag);
    k_grum<<<dim3(12, 96), 512, 0, stream>>>(OB, WH, d_in[9], d_in[10], giE, W0, flag);

    k_colsum<<<12, 256, 0, stream>>>(W0, svec);
    k_matvec<<<3, 256, 0, stream>>>(svec, d_in[6], (size_t)DD * DD, mvec, flag);
    k_rowdot<<<2304, 256, 0, stream>>>(mvec, d_in[7], d_in[9], giE, flag);
    k_grum<<<dim3(12, 96), 512, 0, stream>>>(W0, WH, d_in[9], d_in[10], giE, OB, flag);

    // ---- y = hf + relu(x) for all 3 chunks (OB -> W0); OB then dead ----
    k_build_y<<<4608, 256, 0, stream>>>(hf, OB, W0, flag);

    // ---- heads batched over z: y(W0) -> H(OB) -> T(W0) -> LN(d_out) ----
    k_mgemm<EPI_BIAS_RELU><<<dim3(6, 32, 3), 512, 0, stream>>>(
        W0, NBSD, tailW, 2 * WSLOT, d_in[12], d_in[18], d_in[24], OB, NBSD, flag);
    k_mgemm<EPI_BIAS><<<dim3(6, 32, 3), 512, 0, stream>>>(
        OB, NBSD, tailW + WSLOT, 2 * WSLOT, d_in[14], d_in[20], d_in[26], W0, NBSD, flag);
    k_ln<<<NNODE, 256, 0, stream>>>(W0, d_in[15], d_in[16], d_in[21], d_in[22],
                                    d_in[27], d_in[28], OUTF, flag);
}

// Round 9
// 661.506 us; speedup vs baseline: 1.5181x; 1.2980x over previous
//
#include <hip/hip_runtime.h>
#include <cstdint>
#include <cstddef>

#define DD 768
#define SS 128
#define NNODE 12288            // 3*B*S
#define NBS 4096               // B*S
#define NBSD 3145728           // B*S*D (per-chunk elements)
#define TOTAL_ND 9437184ULL    // NNODE*DD == out_size (fp32 elements)
#define WMAT 589824            // 768*768
#define WSLOT 1179648          // hi+lo pair of one 768x768 matrix (u16 elems)

typedef __attribute__((ext_vector_type(4))) float f32x4;
typedef __attribute__((ext_vector_type(8))) short bf16x8;
typedef __attribute__((ext_vector_type(4))) uint16_t u16x4;
typedef __attribute__((ext_vector_type(2))) uint16_t u16x2;
typedef __attribute__((ext_vector_type(8))) uint16_t u16x8;
typedef __attribute__((ext_vector_type(2))) uint32_t u32x2;

__device__ __forceinline__ float b2f(uint16_t u) {
    union { uint32_t i; float f; } x; x.i = ((uint32_t)u) << 16; return x.f;
}
__device__ __forceinline__ uint16_t f2b(float f) {
    uint32_t x = __float_as_uint(f);
    return (uint16_t)((x + 0x7FFFu + ((x >> 16) & 1u)) >> 16);
}
__device__ __forceinline__ float loadf(const void* p, size_t i, int isf32) {
    return isf32 ? ((const float*)p)[i] : b2f(((const uint16_t*)p)[i]);
}
// feats[n][d] = src_{d%3}[n*256 + d/3]
__device__ __forceinline__ float featAt(const void* hc, const void* hd, const void* hs,
                                        int n, int d, int isf) {
    int w = d % 3;
    size_t u = (size_t)n * 256 + (size_t)(d / 3);
    const void* p = (w == 0) ? hc : (w == 1) ? hd : hs;
    return loadf(p, u, isf);
}
__device__ __forceinline__ uint32_t pk2(uint16_t a, uint16_t b) {
    return (uint32_t)a | ((uint32_t)b << 16);
}

// async 16B global->LDS (linear dest: wave-uniform base + lane*16)
__device__ __forceinline__ void gload16(const uint16_t* g, uint16_t* l) {
    __builtin_amdgcn_global_load_lds(
        (__attribute__((address_space(1))) uint32_t*)(uintptr_t)g,
        (__attribute__((address_space(3))) uint32_t*)l, 16, 0, 0);
}

// ---------- diag beacon ----------
__global__ void k_diag(float* out, float code) {
    if (threadIdx.x == 0 && blockIdx.x == 0) out[0] = code;
}

// ---------- dtype probe ----------
__global__ void k_probe(const void* hf, int* flag) {
    if (threadIdx.x == 0 && blockIdx.x == 0) {
        const uint32_t* w = (const uint32_t*)hf;
        int bad = 0;
        for (int k = 0; k < 64; k++) {
            uint16_t lo = (uint16_t)(w[k] & 0xFFFFu);
            int e = (lo >> 7) & 0xFF;
            if (e < 100 || e > 140) bad++;
        }
        flag[0] = (bad > 24) ? 1 : 0;
    }
}

// ---------- feats build + F128 hi/lo split (merged) ----------
__global__ __launch_bounds__(256) void k_build_all(
    const void* __restrict__ hc, const void* __restrict__ hd,
    const void* __restrict__ hs, uint16_t* __restrict__ feats,
    uint16_t* __restrict__ Fh, uint16_t* __restrict__ Fl,
    const int* __restrict__ flag) {
    int isf = flag[0];
    if (blockIdx.x < 3072) {
        int u = (blockIdx.x * 256 + threadIdx.x) * 4;
        float a[4], b[4], c[4];
        if (isf) {
            f32x4 va = *(const f32x4*)((const float*)hc + u);
            f32x4 vb = *(const f32x4*)((const float*)hd + u);
            f32x4 vc = *(const f32x4*)((const float*)hs + u);
            #pragma unroll
            for (int q = 0; q < 4; q++) { a[q] = va[q]; b[q] = vb[q]; c[q] = vc[q]; }
        } else {
            u16x4 va = *(const u16x4*)((const uint16_t*)hc + u);
            u16x4 vb = *(const u16x4*)((const uint16_t*)hd + u);
            u16x4 vc = *(const u16x4*)((const uint16_t*)hs + u);
            #pragma unroll
            for (int q = 0; q < 4; q++) { a[q] = b2f(va[q]); b[q] = b2f(vb[q]); c[q] = b2f(vc[q]); }
        }
        uint16_t o[12];
        #pragma unroll
        for (int q = 0; q < 4; q++) {
            o[3 * q] = f2b(a[q]); o[3 * q + 1] = f2b(b[q]); o[3 * q + 2] = f2b(c[q]);
        }
        u32x2 w0 = {pk2(o[0], o[1]), pk2(o[2], o[3])};
        u32x2 w1 = {pk2(o[4], o[5]), pk2(o[6], o[7])};
        u32x2 w2 = {pk2(o[8], o[9]), pk2(o[10], o[11])};
        *(u32x2*)(feats + (size_t)3 * u) = w0;
        *(u32x2*)(feats + (size_t)3 * u + 4) = w1;
        *(u32x2*)(feats + (size_t)3 * u + 8) = w2;
    } else {
        int t = (blockIdx.x - 3072) * 256 + threadIdx.x;   // 384 blocks -> 98304
        int n = t / DD, d = t - n * DD;
        float v = featAt(hc, hd, hs, n, d, isf);
        uint16_t h = f2b(v);
        Fh[t] = h;
        Fl[t] = f2b(v - b2f(h));
    }
}

// ---------- G = F F^T via MFMA hi/lo (drops ll term, ~1e-5 rel err) ----------
__global__ __launch_bounds__(256)
void k_simgemm(const uint16_t* __restrict__ Fh, const uint16_t* __restrict__ Fl,
               float* __restrict__ G) {
    __shared__ __align__(16) uint16_t Ah[64 * 32], Al[64 * 32], Bh_[64 * 32], Bl_[64 * 32];
    const int tid = threadIdx.x, lane = tid & 63, wid = tid >> 6;
    const int wr = wid >> 1, wc = wid & 1;
    const int m0 = blockIdx.y * 64, n0 = blockIdx.x * 64;
    f32x4 acc[2][2];
    #pragma unroll
    for (int i = 0; i < 2; i++)
        #pragma unroll
        for (int j = 0; j < 2; j++) acc[i][j] = (f32x4){0.f, 0.f, 0.f, 0.f};
    const int sr = tid >> 2, sg = tid & 3;
    const int sgl = sg ^ ((sr >> 1) & 3);
    const int dofs = wid * 64 * 8;
    for (int k0 = 0; k0 < DD; k0 += 32) {
        gload16(Fh + (size_t)(m0 + sr) * DD + k0 + sgl * 8, Ah + dofs);
        gload16(Fl + (size_t)(m0 + sr) * DD + k0 + sgl * 8, Al + dofs);
        gload16(Fh + (size_t)(n0 + sr) * DD + k0 + sgl * 8, Bh_ + dofs);
        gload16(Fl + (size_t)(n0 + sr) * DD + k0 + sgl * 8, Bl_ + dofs);
        __syncthreads();
        bf16x8 ah[2], al[2], bh2[2], bl2[2];
        #pragma unroll
        for (int i = 0; i < 2; i++) {
            int r = wr * 32 + i * 16 + (lane & 15);
            int g = (lane >> 4) ^ ((r >> 1) & 3);
            ah[i] = *(const bf16x8*)(Ah + r * 32 + g * 8);
            al[i] = *(const bf16x8*)(Al + r * 32 + g * 8);
        }
        #pragma unroll
        for (int j = 0; j < 2; j++) {
            int r = wc * 32 + j * 16 + (lane & 15);
            int g = (lane >> 4) ^ ((r >> 1) & 3);
            bh2[j] = *(const bf16x8*)(Bh_ + r * 32 + g * 8);
            bl2[j] = *(const bf16x8*)(Bl_ + r * 32 + g * 8);
        }
        #pragma unroll
        for (int i = 0; i < 2; i++)
            #pragma unroll
            for (int j = 0; j < 2; j++)
                acc[i][j] = __builtin_amdgcn_mfma_f32_16x16x32_bf16(ah[i], bh2[j], acc[i][j], 0, 0, 0);
        #pragma unroll
        for (int i = 0; i < 2; i++)
            #pragma unroll
            for (int j = 0; j < 2; j++)
                acc[i][j] = __builtin_amdgcn_mfma_f32_16x16x32_bf16(ah[i], bl2[j], acc[i][j], 0, 0, 0);
        #pragma unroll
        for (int i = 0; i < 2; i++)
            #pragma unroll
            for (int j = 0; j < 2; j++)
                acc[i][j] = __builtin_amdgcn_mfma_f32_16x16x32_bf16(al[i], bh2[j], acc[i][j], 0, 0, 0);
        __syncthreads();
    }
    #pragma unroll
    for (int i = 0; i < 2; i++)
        #pragma unroll
        for (int j = 0; j < 2; j++) {
            int n = n0 + wc * 32 + j * 16 + (lane & 15);
            int mb = m0 + wr * 32 + i * 16 + ((lane >> 4) << 2);
            #pragma unroll
            for (int q = 0; q < 4; q++)
                G[(size_t)(mb + q) * SS + n] = acc[i][j][q];
        }
}

// ---------- sim post: nrm from diag -> cos normalize (in place) -> minmax ----------
__global__ __launch_bounds__(256) void k_simpost(float* __restrict__ simb,
                                                 float* __restrict__ mnmx) {
    int tid = threadIdx.x;
    __shared__ float nrmS[SS];
    if (tid < SS) nrmS[tid] = fmaxf(sqrtf(simb[(size_t)tid * SS + tid]), 1e-8f);
    __syncthreads();
    float mn = 3.4e38f, mx = -3.4e38f;
    for (int e = tid; e < SS * SS; e += 256) {
        int i = e >> 7, j = e & 127;
        float v = simb[e] / (nrmS[i] * nrmS[j]);
        simb[e] = v;
        mn = fminf(mn, v); mx = fmaxf(mx, v);
    }
    __shared__ float rmn[256], rmx[256];
    rmn[tid] = mn; rmx[tid] = mx; __syncthreads();
    for (int o = 128; o > 0; o >>= 1) {
        if (tid < o) { rmn[tid] = fminf(rmn[tid], rmn[tid + o]); rmx[tid] = fmaxf(rmx[tid], rmx[tid + o]); }
        __syncthreads();
    }
    if (tid == 0) { mnmx[0] = rmn[0]; mnmx[1] = rmx[0]; }
}

// ---------- min-max normalize sims in place, deg/dinv ----------
__global__ __launch_bounds__(128) void k_deg(float* __restrict__ simb,
                                             const float* __restrict__ mnmx,
                                             float* __restrict__ deg,
                                             float* __restrict__ dinv) {
    int j = blockIdx.x, i = threadIdx.x;
    float mn = mnmx[0], inv = 1.f / (mnmx[1] - mnmx[0]);
    float s = (simb[i * SS + j] - mn) * inv;
    simb[i * SS + j] = s;
    __shared__ float red[128];
    red[i] = s; __syncthreads();
    for (int o = 64; o > 0; o >>= 1) { if (i < o) red[i] += red[i + o]; __syncthreads(); }
    if (i == 0) { float d = red[0] + 1.f; deg[j] = d; dinv[j] = rsqrtf(d); }
}

// ---------- GCN neighbor aggregate (j<128), grid (SS,3) ----------
__global__ __launch_bounds__(256) void k_agg(const float* __restrict__ simb,
                                             const float* __restrict__ dinv,
                                             const uint16_t* __restrict__ xw,
                                             float* __restrict__ aggb) {
    int j = blockIdx.x;
    int d = blockIdx.y * 256 + threadIdx.x;
    __shared__ float w[SS];
    if (threadIdx.x < SS) w[threadIdx.x] = dinv[threadIdx.x] * simb[threadIdx.x * SS + j] * dinv[j];
    __syncthreads();
    float s = 0.f;
    #pragma unroll 8
    for (int i = 0; i < SS; i++) s += w[i] * b2f(xw[(size_t)i * DD + d]);
    aggb[(size_t)j * DD + d] = s;
}

// ---------- GCN combine in place (vec x8, bf16 state) ----------
__global__ __launch_bounds__(256) void k_gcn_combine(uint16_t* __restrict__ xw,
                                                     const float* __restrict__ aggb,
                                                     const float* __restrict__ deg,
                                                     const void* __restrict__ gcnb,
                                                     const int* __restrict__ flag) {
    uint32_t t = (blockIdx.x * 256 + threadIdx.x) * 8u;   // 4608 blocks, exact
    int isf = flag[0];
    uint32_t n = t / 768u;
    uint32_t d0 = t - n * 768u;
    u16x8 xv = *(const u16x8*)(xw + t);
    float v[8];
    #pragma unroll
    for (int q = 0; q < 8; q++) v[q] = b2f(xv[q]);
    if (n < SS) {
        f32x4 a0 = *(const f32x4*)(aggb + t);
        f32x4 a1 = *(const f32x4*)(aggb + t + 4);
        float dg = deg[n];
        #pragma unroll
        for (int q = 0; q < 4; q++) { v[q] = v[q] / dg + a0[q]; v[q + 4] = v[q + 4] / dg + a1[q]; }
    }
    float bb[8];
    if (isf) {
        f32x4 b0 = *(const f32x4*)((const float*)gcnb + d0);
        f32x4 b1 = *(const f32x4*)((const float*)gcnb + d0 + 4);
        #pragma unroll
        for (int q = 0; q < 4; q++) { bb[q] = b0[q]; bb[q + 4] = b1[q]; }
    } else {
        u16x8 b8 = *(const u16x8*)((const uint16_t*)gcnb + d0);
        #pragma unroll
        for (int q = 0; q < 8; q++) bb[q] = b2f(b8[q]);
    }
    u16x8 ov;
    #pragma unroll
    for (int q = 0; q < 8; q++) ov[q] = f2b(fmaxf(v[q] + bb[q], 0.f));
    *(u16x8*)(xw + t) = ov;
}

// ---------- colsum over first 128 rows (12 blocks, 4-way row split) ----------
// also zeroes mvec (written before any sync; matvec runs strictly after)
__global__ __launch_bounds__(256) void k_colsum(const uint16_t* __restrict__ x,
                                                float* __restrict__ svec,
                                                float* __restrict__ mvec) {
    if (blockIdx.x == 0) {
        mvec[threadIdx.x] = 0.f;
        mvec[threadIdx.x + 256] = 0.f;
        mvec[threadIdx.x + 512] = 0.f;
    }
    int d = blockIdx.x * 64 + (threadIdx.x & 63);
    int part = threadIdx.x >> 6;
    float s = 0.f;
    for (int i = part * 32; i < part * 32 + 32; i++) s += b2f(x[(size_t)i * DD + d]);
    __shared__ float red[256];
    red[threadIdx.x] = s; __syncthreads();
    if (part == 0)
        svec[d] = red[threadIdx.x] + red[threadIdx.x + 64] +
                  red[threadIdx.x + 128] + red[threadIdx.x + 192];
}

// ---------- mvec = svec @ ggc_W[l], d-parallel with atomicAdd ----------
// grid (3,16): 256 k-cols x 48 d-rows per block; coalesced row-major reads.
__global__ __launch_bounds__(256) void k_matvec(const float* __restrict__ svec,
                                                const void* __restrict__ Wg, size_t ofs,
                                                float* __restrict__ mvec,
                                                const int* __restrict__ flag) {
    int k = blockIdx.x * 256 + threadIdx.x;
    int d0 = blockIdx.y * 48;
    int isf = flag[0];
    float s = 0.f;
    #pragma unroll 8
    for (int d = d0; d < d0 + 48; d++)
        s += svec[d] * loadf(Wg, ofs + (size_t)d * DD + k, isf);
    atomicAdd(&mvec[k], s);
}

// ---------- giE = mvec @ wih.T + bih ----------
__global__ __launch_bounds__(256) void k_rowdot(const float* __restrict__ mvec,
                                                const void* __restrict__ wih,
                                                const void* __restrict__ bih,
                                                float* __restrict__ giE,
                                                const int* __restrict__ flag) {
    int rr = blockIdx.x, tid = threadIdx.x;
    int isf = flag[0];
    float s = 0.f;
    for (int k = tid; k < DD; k += 256) s += mvec[k] * loadf(wih, (size_t)rr * DD + k, isf);
    __shared__ float red[256];
    red[tid] = s; __syncthreads();
    for (int o = 128; o > 0; o >>= 1) { if (tid < o) red[tid] += red[tid + o]; __syncthreads(); }
    if (tid == 0) giE[rr] = red[0] + loadf(bih, rr, isf);
}

// ---------- y = h_feature + relu(x_g), batched all 3 chunks, vec x8 ----------
__global__ __launch_bounds__(256) void k_build_y(const void* __restrict__ hf,
                                                 const uint16_t* __restrict__ xg,
                                                 uint16_t* __restrict__ y,
                                                 const int* __restrict__ flag) {
    uint32_t t = (blockIdx.x * 256 + threadIdx.x) * 8u;   // 4608 blocks, exact TOTAL_ND
    int isf = flag[0];
    uint32_t u = t;
    if (u >= 2u * NBSD) u -= 2u * NBSD; else if (u >= NBSD) u -= NBSD;
    u16x8 xv = *(const u16x8*)(xg + t);
    float h[8];
    if (isf) {
        f32x4 h0 = *(const f32x4*)((const float*)hf + u);
        f32x4 h1 = *(const f32x4*)((const float*)hf + u + 4);
        #pragma unroll
        for (int q = 0; q < 4; q++) { h[q] = h0[q]; h[q + 4] = h1[q]; }
    } else {
        u16x8 h8 = *(const u16x8*)((const uint16_t*)hf + u);
        #pragma unroll
        for (int q = 0; q < 8; q++) h[q] = b2f(h8[q]);
    }
    u16x8 ov;
    #pragma unroll
    for (int q = 0; q < 8; q++) ov[q] = f2b(h[q] + fmaxf(b2f(xv[q]), 0.f));
    *(u16x8*)(y + t) = ov;
}

// ---------- LayerNorm (batched: 12288 rows, per-g weight select) ----------
__global__ __launch_bounds__(256) void k_ln(const uint16_t* __restrict__ tin,
                                            const void* g0, const void* b0,
                                            const void* g1, const void* b1,
                                            const void* g2, const void* b2,
                                            float* __restrict__ out,
                                            const int* __restrict__ flag) {
    int m = blockIdx.x, tid = threadIdx.x;
    int isf = flag[0];
    int gs = m >> 12;
    const void* gw = (gs == 0) ? g0 : (gs == 1) ? g1 : g2;
    const void* bw = (gs == 0) ? b0 : (gs == 1) ? b1 : b2;
    float v0 = b2f(tin[(size_t)m * DD + tid]);
    float v1 = b2f(tin[(size_t)m * DD + tid + 256]);
    float v2 = b2f(tin[(size_t)m * DD + tid + 512]);
    __shared__ float red[256];
    red[tid] = v0 + v1 + v2; __syncthreads();
    for (int o = 128; o > 0; o >>= 1) { if (tid < o) red[tid] += red[tid + o]; __syncthreads(); }
    float mu = red[0] * (1.f / 768.f);
    __syncthreads();
    float d0 = v0 - mu, d1 = v1 - mu, d2 = v2 - mu;
    red[tid] = d0 * d0 + d1 * d1 + d2 * d2; __syncthreads();
    for (int o = 128; o > 0; o >>= 1) { if (tid < o) red[tid] += red[tid + o]; __syncthreads(); }
    float rstd = rsqrtf(red[0] * (1.f / 768.f) + 1e-5f);
    out[(size_t)m * DD + tid]       = d0 * rstd * loadf(gw, tid, isf)       + loadf(bw, tid, isf);
    out[(size_t)m * DD + tid + 256] = d1 * rstd * loadf(gw, tid + 256, isf) + loadf(bw, tid + 256, isf);
    out[(size_t)m * DD + tid + 512] = d2 * rstd * loadf(gw, tid + 512, isf) + loadf(bw, tid + 512, isf);
}

// ---------- weight convert: hi-only bf16, elementwise vec x4 (whh) ----------
__global__ __launch_bounds__(256) void k_cvt1(const void* __restrict__ src,
                                              uint16_t* __restrict__ dh, int n,
                                              const int* __restrict__ flag) {
    int t = (blockIdx.x * 256 + threadIdx.x) * 4;   // exact cover
    int isf = flag[0];
    u16x4 hh;
    if (isf) {
        f32x4 s = *(const f32x4*)((const float*)src + t);
        #pragma unroll
        for (int q = 0; q < 4; q++) hh[q] = f2b(s[q]);
    } else {
        hh = *(const u16x4*)((const uint16_t*)src + t);
    }
    *(u16x4*)(dh + t) = hh;
}

// ---------- weight convert: transpose + hi/lo split, 7 matrices batched ----------
__global__ __launch_bounds__(256) void k_cvtT7(const void* s0, const void* s1,
                                               const void* s2, const void* s3,
                                               const void* s4, const void* s5,
                                               const void* s6,
                                               uint16_t* __restrict__ gdst,
                                               uint16_t* __restrict__ tail,
                                               const int* __restrict__ flag) {
    __shared__ float tile[64][65];
    int isf = flag[0];
    int z = blockIdx.z;
    const void* src = (z == 0) ? s0 : (z == 1) ? s1 : (z == 2) ? s2 :
                      (z == 3) ? s3 : (z == 4) ? s4 : (z == 5) ? s5 : s6;
    uint16_t* dh = (z == 0) ? gdst : tail + (size_t)(z - 1) * WSLOT;
    uint16_t* dl = dh + WMAT;
    int k0 = blockIdx.x * 64, n0 = blockIdx.y * 64;
    for (int t = threadIdx.x; t < 4096; t += 256) {
        int r = t >> 6, c = t & 63;
        tile[r][c] = loadf(src, (size_t)(k0 + r) * DD + n0 + c, isf);
    }
    __syncthreads();
    for (int base = 0; base < 4096; base += 512) {
        int t = base + threadIdx.x * 2;
        int r = t >> 6, c = t & 63;
        float va = tile[c][r], vb = tile[c + 1][r];
        uint16_t ha = f2b(va), hb = f2b(vb);
        size_t o = (size_t)(n0 + r) * DD + k0 + c;
        *(u16x2*)(dh + o) = (u16x2){ha, hb};
        *(u16x2*)(dl + o) = (u16x2){f2b(va - b2f(ha)), f2b(vb - b2f(hb))};
    }
}

// =============== MFMA GEMM: C[M,768] = A[M,768] @ BT^T, bf16 hi/lo combined ====
// 128x128 tile, BK=32, 8 waves (512 thr): per-wave 32x64, acc=32 floats.
// Single-buffer m97-style loop; occupancy (not ILP) hides staging latency.
enum { EPI_NONE = 0, EPI_BIAS_RELU = 3, EPI_BIAS = 4 };

template<int EPI, int ISF>
__device__ __forceinline__ void mgemm_core(
    const uint16_t* __restrict__ Az, const uint16_t* __restrict__ Bh,
    const uint16_t* __restrict__ Bl, const void* bias,
    uint16_t* __restrict__ Cz, uint16_t* As, uint16_t* Bs, int m0, int n0) {
    const int tid = threadIdx.x, lane = tid & 63;
    const int wid = tid >> 6;                  // 0..7
    const int wr = wid >> 1, wc = wid & 1;     // 4 M-quads x 2 N-halves

    f32x4 acc[2][4];
    #pragma unroll
    for (int i = 0; i < 2; i++)
        #pragma unroll
        for (int j = 0; j < 4; j++) acc[i][j] = (f32x4){0.f, 0.f, 0.f, 0.f};

    // staging indices: 512 chunks of 16B cover a 128x32 tile (4 groups/row)
    const int scr = tid >> 2;                              // row 0..127
    const int sgl = (tid & 3) ^ ((scr >> 1) & 3);          // swizzled group
    const int sdst = tid * 8;                              // wave-linear dest

    int offA[2], offB[4];
    #pragma unroll
    for (int i = 0; i < 2; i++) {
        int r = wr * 32 + i * 16 + (lane & 15);
        offA[i] = r * 32 + (((lane >> 4) ^ ((r >> 1) & 3)) << 3);
    }
    #pragma unroll
    for (int j = 0; j < 4; j++) {
        int r = wc * 64 + j * 16 + (lane & 15);
        offB[j] = r * 32 + (((lane >> 4) ^ ((r >> 1) & 3)) << 3);
    }

    for (int k0 = 0; k0 < DD; k0 += 32) {
        gload16(Az + (size_t)(m0 + scr) * DD + k0 + sgl * 8, As + sdst);
        gload16(Bh + (size_t)(n0 + scr) * DD + k0 + sgl * 8, Bs + sdst);
        if (ISF) gload16(Bl + (size_t)(n0 + scr) * DD + k0 + sgl * 8, Bs + 4096 + sdst);
        __syncthreads();
        bf16x8 af[2], b4[4], l4[4];
        #pragma unroll
        for (int i = 0; i < 2; i++) af[i] = *(const bf16x8*)(As + offA[i]);
        #pragma unroll
        for (int j = 0; j < 4; j++) {
            b4[j] = *(const bf16x8*)(Bs + offB[j]);
            if (ISF) l4[j] = *(const bf16x8*)(Bs + 4096 + offB[j]);
        }
        #pragma unroll
        for (int i = 0; i < 2; i++)
            #pragma unroll
            for (int j = 0; j < 4; j++)
                acc[i][j] = __builtin_amdgcn_mfma_f32_16x16x32_bf16(af[i], b4[j], acc[i][j], 0, 0, 0);
        if (ISF) {
            #pragma unroll
            for (int i = 0; i < 2; i++)
                #pragma unroll
                for (int j = 0; j < 4; j++)
                    acc[i][j] = __builtin_amdgcn_mfma_f32_16x16x32_bf16(af[i], l4[j], acc[i][j], 0, 0, 0);
        }
        __syncthreads();
    }
    // D layout: col = lane&15, row = (lane>>4)*4 + q
    #pragma unroll
    for (int i = 0; i < 2; i++) {
        #pragma unroll
        for (int j = 0; j < 4; j++) {
            int n = n0 + wc * 64 + j * 16 + (lane & 15);
            int mb = m0 + wr * 32 + i * 16 + ((lane >> 4) << 2);
            float bv = 0.f;
            if (EPI != EPI_NONE) bv = loadf(bias, n, ISF);
            #pragma unroll
            for (int q = 0; q < 4; q++) {
                float v = acc[i][j][q];
                if (EPI == EPI_BIAS_RELU) v = fmaxf(v + bv, 0.f);
                else if (EPI == EPI_BIAS) v = v + bv;
                Cz[(size_t)(mb + q) * DD + n] = f2b(v);
            }
        }
    }
}

template<int EPI>
__global__ __launch_bounds__(512, 4)
void k_mgemm(const uint16_t* __restrict__ A, uint32_t aZ,
             const uint16_t* __restrict__ BTh, uint32_t bZ,
             const void* bias0, const void* bias1, const void* bias2,
             uint16_t* __restrict__ C, uint32_t cZ,
             const int* __restrict__ flag) {
    __shared__ __align__(16) uint16_t As[4096];      // 128x32
    __shared__ __align__(16) uint16_t Bs[2 * 4096];  // hi/lo
    const int isf = flag[0];
    const int z = blockIdx.z;
    const uint16_t* Az = A + (size_t)z * aZ;
    const uint16_t* Bh = BTh + (size_t)z * bZ;
    const uint16_t* Bl = Bh + WMAT;
    uint16_t* Cz = C + (size_t)z * cZ;
    const void* bias = (z == 0) ? bias0 : (z == 1) ? bias1 : bias2;
    const int m0 = blockIdx.y * 128, n0 = blockIdx.x * 128;
    if (isf) mgemm_core<EPI, 1>(Az, Bh, Bl, bias, Cz, As, Bs, m0, n0);
    else     mgemm_core<EPI, 0>(Az, Bh, Bl, bias, Cz, As, Bs, m0, n0);
}

// =============== MFMA fused GRU layer: 3-gate GEMM (whh hi-only) + cell ====
// Tile M=128 x (3 gates x 64), 8 waves (512 thr): per-wave 32M x 32N/gate,
// acc = 48 floats. Single-buffer loop; grid (12, 96). whh bf16 hi only:
// B-lo error ~1e-3 abs on gate pre-activations, << trunk bf16 error floor.
template<int ISF>
__device__ __forceinline__ void grum_core(
    const uint16_t* __restrict__ X,
    const uint16_t* __restrict__ Wh,
    const void* __restrict__ bih, const void* __restrict__ bhh,
    const float* __restrict__ giE, uint16_t* __restrict__ Xn,
    uint16_t* As, uint16_t* Bs, int m0, int n0) {
    const int tid = threadIdx.x, lane = tid & 63;
    const int wid = tid >> 6;                  // 0..7
    const int wr = wid >> 1, wc = wid & 1;     // 4 M-quads x 2 N-halves

    f32x4 acc[3][2][2];
    #pragma unroll
    for (int gg = 0; gg < 3; gg++)
        #pragma unroll
        for (int i = 0; i < 2; i++)
            #pragma unroll
            for (int j = 0; j < 2; j++) acc[gg][i][j] = (f32x4){0.f, 0.f, 0.f, 0.f};

    // A staging: 512 chunks cover 128x32
    const int acr = tid >> 2;
    const int agl = (tid & 3) ^ ((acr >> 1) & 3);
    // B staging: threads 0..255 stage 3 gates (hi only), 256 chunks per gate
    const int bc = tid & 255;
    const int bcr = bc >> 2;
    const int bgl = (bc & 3) ^ ((bcr >> 1) & 3);

    int offA[2], offB[2];
    #pragma unroll
    for (int i = 0; i < 2; i++) {
        int r = wr * 32 + i * 16 + (lane & 15);
        offA[i] = r * 32 + (((lane >> 4) ^ ((r >> 1) & 3)) << 3);
    }
    #pragma unroll
    for (int j = 0; j < 2; j++) {
        int r = wc * 32 + j * 16 + (lane & 15);
        offB[j] = r * 32 + (((lane >> 4) ^ ((r >> 1) & 3)) << 3);
    }

    for (int k0 = 0; k0 < DD; k0 += 32) {
        gload16(X + (size_t)(m0 + acr) * DD + k0 + agl * 8, As + tid * 8);
        if (tid < 256) {
            #pragma unroll
            for (int gg = 0; gg < 3; gg++)
                gload16(Wh + (size_t)(gg * DD + n0 + bcr) * DD + k0 + bgl * 8,
                        Bs + gg * 2048 + bc * 8);
        }
        __syncthreads();
        bf16x8 af[2];
        #pragma unroll
        for (int i = 0; i < 2; i++) af[i] = *(const bf16x8*)(As + offA[i]);
        #pragma unroll
        for (int gg = 0; gg < 3; gg++) {
            const uint16_t* Bhc = Bs + gg * 2048;
            bf16x8 bh2[2];
            #pragma unroll
            for (int j = 0; j < 2; j++) bh2[j] = *(const bf16x8*)(Bhc + offB[j]);
            #pragma unroll
            for (int j = 0; j < 2; j++)
                #pragma unroll
                for (int i = 0; i < 2; i++)
                    acc[gg][i][j] = __builtin_amdgcn_mfma_f32_16x16x32_bf16(af[i], bh2[j], acc[gg][i][j], 0, 0, 0);
        }
        __syncthreads();
    }
    // epilogue: full GRU cell pointwise
    #pragma unroll
    for (int j = 0; j < 2; j++) {
        int n = n0 + wc * 32 + j * 16 + (lane & 15);
        float bh0 = loadf(bhh, n, ISF);
        float bh1 = loadf(bhh, DD + n, ISF);
        float bh2v = loadf(bhh, 2 * DD + n, ISF);
        float gE0 = giE[n], gE1 = giE[DD + n], gE2 = giE[2 * DD + n];
        float bi0 = loadf(bih, n, ISF);
        float bi1 = loadf(bih, DD + n, ISF);
        float bi2 = loadf(bih, 2 * DD + n, ISF);
        #pragma unroll
        for (int i = 0; i < 2; i++) {
            int mb = m0 + wr * 32 + i * 16 + ((lane >> 4) << 2);
            #pragma unroll
            for (int q = 0; q < 4; q++) {
                int m = mb + q;
                bool msg = (m < SS);
                float gr = msg ? gE0 : bi0;
                float gz = msg ? gE1 : bi1;
                float gn = msg ? gE2 : bi2;
                float rg = 1.f / (1.f + expf(-(acc[0][i][j][q] + bh0 + gr)));
                float zg = 1.f / (1.f + expf(-(acc[1][i][j][q] + bh1 + gz)));
                float hn = acc[2][i][j][q] + bh2v;
                float nn = tanhf(gn + rg * hn);
                float xo = b2f(X[(size_t)m * DD + n]);
                Xn[(size_t)m * DD + n] = f2b((1.f - zg) * nn + zg * xo);
            }
        }
    }
}

__global__ __launch_bounds__(512, 4)
void k_grum(const uint16_t* __restrict__ X,
            const uint16_t* __restrict__ Wh,
            const void* __restrict__ bih, const void* __restrict__ bhh,
            const float* __restrict__ giE, uint16_t* __restrict__ Xn,
            const int* __restrict__ flag) {
    __shared__ __align__(16) uint16_t As[4096];          // 128x32 (8KB)
    __shared__ __align__(16) uint16_t Bs[3 * 2048];      // 3 gates x 64x32 hi (12KB)
    const int n0 = blockIdx.x * 64, m0 = blockIdx.y * 128;
    if (flag[0]) grum_core<1>(X, Wh, bih, bhh, giE, Xn, As, Bs, m0, n0);
    else         grum_core<0>(X, Wh, bih, bhh, giE, Xn, As, Bs, m0, n0);
}

// ============================== driver ==============================
extern "C" void kernel_launch(void* const* d_in, const int* in_sizes, int n_in,
                              void* d_out, int out_size, void* d_ws, size_t ws_size,
                              hipStream_t stream) {
    float* OUTF = (float*)d_out;            // FINAL output: fp32
    uint16_t* OB = (uint16_t*)d_out;        // first 18.9MB of d_out as bf16 trunk/H scratch

    static const int expect[29] = {
        3145728,3145728,3145728,3145728, 589824,768, 1179648, 1769472,1769472, 2304,2304,
        589824,768,589824,768,768,768,
        589824,768,589824,768,768,768,
        589824,768,589824,768,768,768 };
    int bad = -1;
    if (n_in != 29) bad = 90;
    else { for (int i = 0; i < 29; i++) if (in_sizes[i] != expect[i]) { bad = i; break; } }
    if (bad < 0 && out_size != (int)TOTAL_ND) bad = 91;
    if (bad < 0 && ws_size < 33ull * 1024 * 1024) bad = 92;
    if (bad >= 0) {
        k_diag<<<1, 64, 0, stream>>>(OUTF, 10000.f + 100.f * (float)bad);
        return;
    }

    // ws layout (floats): small scratch | F128 hi/lo | W0 | WH | WT  (~30.8 MiB)
    float* fbase = (float*)d_ws;
    float* simb = fbase;                        // 16384
    float* mnmx = simb + 16384;                 // 2
    float* deg  = mnmx + 2;                     // 128
    float* dinv = deg + 128;                    // 128
    float* aggb = dinv + 128;                   // 98304
    float* svec = aggb + 98304;                 // 768
    float* mvec = svec + 768;                   // 768
    float* giE  = mvec + 768;                   // 2304
    int*   flag = (int*)(giE + 2304);           // 1
    uint16_t* F128h = (uint16_t*)(fbase + 118916);  // 98304 u16
    uint16_t* F128l = (uint16_t*)(fbase + 168068);  // 98304 u16
    uint16_t* W0 = (uint16_t*)(fbase + 217220);     // 9,437,184 u16
    uint16_t* WH = W0 + TOTAL_ND;                   // 3,145,728 u16 slots
    uint16_t* WT = WH + NBSD;                       // 3,145,728 u16 slots (spare)

    // head weights hi/lo live in the TAIL of d_out (last 13.5 MB; dead before LN)
    uint16_t* tailW = (uint16_t*)((char*)d_out + 23592960);  // 6 slots x WSLOT

    const void* hf = d_in[0];
    const void* hc = d_in[1];
    const void* hd = d_in[2];
    const void* hs = d_in[3];

    k_probe<<<1, 64, 0, stream>>>(hf, flag);

    // ---- all transpose-weight conversions batched (gcn_W -> WH, heads -> tail) ----
    k_cvtT7<<<dim3(12, 12, 7), 256, 0, stream>>>(
        d_in[4], d_in[11], d_in[13], d_in[17], d_in[19], d_in[23], d_in[25],
        WH, tailW, flag);

    // ---- GCN front-end ----
    k_build_all<<<3456, 256, 0, stream>>>(hc, hd, hs, W0, F128h, F128l, flag);
    k_simgemm<<<dim3(2, 2), 256, 0, stream>>>(F128h, F128l, simb);
    k_simpost<<<1, 256, 0, stream>>>(simb, mnmx);
    k_deg<<<SS, SS, 0, stream>>>(simb, mnmx, deg, dinv);
    k_mgemm<EPI_NONE><<<dim3(6, 96, 1), 512, 0, stream>>>(
        W0, 0, WH, 0, nullptr, nullptr, nullptr, OB, 0, flag);
    k_agg<<<dim3(SS, 3), 256, 0, stream>>>(simb, dinv, OB, aggb);
    k_gcn_combine<<<4608, 256, 0, stream>>>(OB, aggb, deg, d_in[5], flag);

    // ---- GatedGraphConv: whh -> WH bf16 hi only (gcn_W in WH now dead) ----
    k_cvt1<<<1728, 256, 0, stream>>>(d_in[8], WH, 1769472, flag);

    k_colsum<<<12, 256, 0, stream>>>(OB, svec, mvec);
    k_matvec<<<dim3(3, 16), 256, 0, stream>>>(svec, d_in[6], 0, mvec, flag);
    k_rowdot<<<2304, 256, 0, stream>>>(mvec, d_in[7], d_in[9], giE, flag);
    k_grum<<<dim3(12, 96), 512, 0, stream>>>(OB, WH, d_in[9], d_in[10], giE, W0, flag);

    k_colsum<<<12, 256, 0, stream>>>(W0, svec, mvec);
    k_matvec<<<dim3(3, 16), 256, 0, stream>>>(svec, d_in[6], (size_t)DD * DD, mvec, flag);
    k_rowdot<<<2304, 256, 0, stream>>>(mvec, d_in[7], d_in[9], giE, flag);
    k_grum<<<dim3(12, 96), 512, 0, stream>>>(W0, WH, d_in[9], d_in[10], giE, OB, flag);

    // ---- y = hf + relu(x) for all 3 chunks (OB -> W0); OB then dead ----
    k_build_y<<<4608, 256, 0, stream>>>(hf, OB, W0, flag);

    // ---- heads batched over z: y(W0) -> H(OB) -> T(W0) -> LN(d_out) ----
    k_mgemm<EPI_BIAS_RELU><<<dim3(6, 32, 3), 512, 0, stream>>>(
        W0, NBSD, tailW, 2 * WSLOT, d_in[12], d_in[18], d_in[24], OB, NBSD, flag);
    k_mgemm<EPI_BIAS><<<dim3(6, 32, 3), 512, 0, stream>>>(
        OB, NBSD, tailW + WSLOT, 2 * WSLOT, d_in[14], d_in[20], d_in[26], W0, NBSD, flag);
    k_ln<<<NNODE, 256, 0, stream>>>(W0, d_in[15], d_in[16], d_in[21], d_in[22],
                                    d_in[27], d_in[28], OUTF, flag);
}

// Round 10
// 627.022 us; speedup vs baseline: 1.6016x; 1.0550x over previous
//
#include <hip/hip_runtime.h>
#include <cstdint>
#include <cstddef>

#define DD 768
#define SS 128
#define NNODE 12288            // 3*B*S
#define NBS 4096               // B*S
#define NBSD 3145728           // B*S*D (per-chunk elements)
#define TOTAL_ND 9437184ULL    // NNODE*DD == out_size (fp32 elements)
#define WMAT 589824            // 768*768
#define WSLOT 1179648          // hi+lo pair of one 768x768 matrix (u16 elems)

typedef __attribute__((ext_vector_type(4))) float f32x4;
typedef __attribute__((ext_vector_type(8))) short bf16x8;
typedef __attribute__((ext_vector_type(4))) uint16_t u16x4;
typedef __attribute__((ext_vector_type(2))) uint16_t u16x2;
typedef __attribute__((ext_vector_type(8))) uint16_t u16x8;
typedef __attribute__((ext_vector_type(2))) uint32_t u32x2;

__device__ __forceinline__ float b2f(uint16_t u) {
    union { uint32_t i; float f; } x; x.i = ((uint32_t)u) << 16; return x.f;
}
__device__ __forceinline__ uint16_t f2b(float f) {
    uint32_t x = __float_as_uint(f);
    return (uint16_t)((x + 0x7FFFu + ((x >> 16) & 1u)) >> 16);
}
__device__ __forceinline__ float loadf(const void* p, size_t i, int isf32) {
    return isf32 ? ((const float*)p)[i] : b2f(((const uint16_t*)p)[i]);
}
// feats[n][d] = src_{d%3}[n*256 + d/3]
__device__ __forceinline__ float featAt(const void* hc, const void* hd, const void* hs,
                                        int n, int d, int isf) {
    int w = d % 3;
    size_t u = (size_t)n * 256 + (size_t)(d / 3);
    const void* p = (w == 0) ? hc : (w == 1) ? hd : hs;
    return loadf(p, u, isf);
}
__device__ __forceinline__ uint32_t pk2(uint16_t a, uint16_t b) {
    return (uint32_t)a | ((uint32_t)b << 16);
}

// async 16B global->LDS (linear dest: wave-uniform base + lane*16)
__device__ __forceinline__ void gload16(const uint16_t* g, uint16_t* l) {
    __builtin_amdgcn_global_load_lds(
        (__attribute__((address_space(1))) uint32_t*)(uintptr_t)g,
        (__attribute__((address_space(3))) uint32_t*)l, 16, 0, 0);
}

// ---------- diag beacon ----------
__global__ void k_diag(float* out, float code) {
    if (threadIdx.x == 0 && blockIdx.x == 0) out[0] = code;
}

// ---------- dtype probe ----------
__global__ void k_probe(const void* hf, int* flag) {
    if (threadIdx.x == 0 && blockIdx.x == 0) {
        const uint32_t* w = (const uint32_t*)hf;
        int bad = 0;
        for (int k = 0; k < 64; k++) {
            uint16_t lo = (uint16_t)(w[k] & 0xFFFFu);
            int e = (lo >> 7) & 0xFF;
            if (e < 100 || e > 140) bad++;
        }
        flag[0] = (bad > 24) ? 1 : 0;
    }
}

// ---------- feats build + F128 hi/lo split (merged) ----------
__global__ __launch_bounds__(256) void k_build_all(
    const void* __restrict__ hc, const void* __restrict__ hd,
    const void* __restrict__ hs, uint16_t* __restrict__ feats,
    uint16_t* __restrict__ Fh, uint16_t* __restrict__ Fl,
    const int* __restrict__ flag) {
    int isf = flag[0];
    if (blockIdx.x < 3072) {
        int u = (blockIdx.x * 256 + threadIdx.x) * 4;
        float a[4], b[4], c[4];
        if (isf) {
            f32x4 va = *(const f32x4*)((const float*)hc + u);
            f32x4 vb = *(const f32x4*)((const float*)hd + u);
            f32x4 vc = *(const f32x4*)((const float*)hs + u);
            #pragma unroll
            for (int q = 0; q < 4; q++) { a[q] = va[q]; b[q] = vb[q]; c[q] = vc[q]; }
        } else {
            u16x4 va = *(const u16x4*)((const uint16_t*)hc + u);
            u16x4 vb = *(const u16x4*)((const uint16_t*)hd + u);
            u16x4 vc = *(const u16x4*)((const uint16_t*)hs + u);
            #pragma unroll
            for (int q = 0; q < 4; q++) { a[q] = b2f(va[q]); b[q] = b2f(vb[q]); c[q] = b2f(vc[q]); }
        }
        uint16_t o[12];
        #pragma unroll
        for (int q = 0; q < 4; q++) {
            o[3 * q] = f2b(a[q]); o[3 * q + 1] = f2b(b[q]); o[3 * q + 2] = f2b(c[q]);
        }
        u32x2 w0 = {pk2(o[0], o[1]), pk2(o[2], o[3])};
        u32x2 w1 = {pk2(o[4], o[5]), pk2(o[6], o[7])};
        u32x2 w2 = {pk2(o[8], o[9]), pk2(o[10], o[11])};
        *(u32x2*)(feats + (size_t)3 * u) = w0;
        *(u32x2*)(feats + (size_t)3 * u + 4) = w1;
        *(u32x2*)(feats + (size_t)3 * u + 8) = w2;
    } else {
        int t = (blockIdx.x - 3072) * 256 + threadIdx.x;   // 384 blocks -> 98304
        int n = t / DD, d = t - n * DD;
        float v = featAt(hc, hd, hs, n, d, isf);
        uint16_t h = f2b(v);
        Fh[t] = h;
        Fl[t] = f2b(v - b2f(h));
    }
}

// ---------- G = F F^T via MFMA hi/lo (drops ll term, ~1e-5 rel err) ----------
__global__ __launch_bounds__(256)
void k_simgemm(const uint16_t* __restrict__ Fh, const uint16_t* __restrict__ Fl,
               float* __restrict__ G) {
    __shared__ __align__(16) uint16_t Ah[64 * 32], Al[64 * 32], Bh_[64 * 32], Bl_[64 * 32];
    const int tid = threadIdx.x, lane = tid & 63, wid = tid >> 6;
    const int wr = wid >> 1, wc = wid & 1;
    const int m0 = blockIdx.y * 64, n0 = blockIdx.x * 64;
    f32x4 acc[2][2];
    #pragma unroll
    for (int i = 0; i < 2; i++)
        #pragma unroll
        for (int j = 0; j < 2; j++) acc[i][j] = (f32x4){0.f, 0.f, 0.f, 0.f};
    const int sr = tid >> 2, sg = tid & 3;
    const int sgl = sg ^ ((sr >> 1) & 3);
    const int dofs = wid * 64 * 8;
    for (int k0 = 0; k0 < DD; k0 += 32) {
        gload16(Fh + (size_t)(m0 + sr) * DD + k0 + sgl * 8, Ah + dofs);
        gload16(Fl + (size_t)(m0 + sr) * DD + k0 + sgl * 8, Al + dofs);
        gload16(Fh + (size_t)(n0 + sr) * DD + k0 + sgl * 8, Bh_ + dofs);
        gload16(Fl + (size_t)(n0 + sr) * DD + k0 + sgl * 8, Bl_ + dofs);
        __syncthreads();
        bf16x8 ah[2], al[2], bh2[2], bl2[2];
        #pragma unroll
        for (int i = 0; i < 2; i++) {
            int r = wr * 32 + i * 16 + (lane & 15);
            int g = (lane >> 4) ^ ((r >> 1) & 3);
            ah[i] = *(const bf16x8*)(Ah + r * 32 + g * 8);
            al[i] = *(const bf16x8*)(Al + r * 32 + g * 8);
        }
        #pragma unroll
        for (int j = 0; j < 2; j++) {
            int r = wc * 32 + j * 16 + (lane & 15);
            int g = (lane >> 4) ^ ((r >> 1) & 3);
            bh2[j] = *(const bf16x8*)(Bh_ + r * 32 + g * 8);
            bl2[j] = *(const bf16x8*)(Bl_ + r * 32 + g * 8);
        }
        #pragma unroll
        for (int i = 0; i < 2; i++)
            #pragma unroll
            for (int j = 0; j < 2; j++)
                acc[i][j] = __builtin_amdgcn_mfma_f32_16x16x32_bf16(ah[i], bh2[j], acc[i][j], 0, 0, 0);
        #pragma unroll
        for (int i = 0; i < 2; i++)
            #pragma unroll
            for (int j = 0; j < 2; j++)
                acc[i][j] = __builtin_amdgcn_mfma_f32_16x16x32_bf16(ah[i], bl2[j], acc[i][j], 0, 0, 0);
        #pragma unroll
        for (int i = 0; i < 2; i++)
            #pragma unroll
            for (int j = 0; j < 2; j++)
                acc[i][j] = __builtin_amdgcn_mfma_f32_16x16x32_bf16(al[i], bh2[j], acc[i][j], 0, 0, 0);
        __syncthreads();
    }
    #pragma unroll
    for (int i = 0; i < 2; i++)
        #pragma unroll
        for (int j = 0; j < 2; j++) {
            int n = n0 + wc * 32 + j * 16 + (lane & 15);
            int mb = m0 + wr * 32 + i * 16 + ((lane >> 4) << 2);
            #pragma unroll
            for (int q = 0; q < 4; q++)
                G[(size_t)(mb + q) * SS + n] = acc[i][j][q];
        }
}

// ---------- sim post: nrm from diag -> cos normalize (in place) -> minmax ----------
__global__ __launch_bounds__(256) void k_simpost(float* __restrict__ simb,
                                                 float* __restrict__ mnmx) {
    int tid = threadIdx.x;
    __shared__ float nrmS[SS];
    if (tid < SS) nrmS[tid] = fmaxf(sqrtf(simb[(size_t)tid * SS + tid]), 1e-8f);
    __syncthreads();
    float mn = 3.4e38f, mx = -3.4e38f;
    for (int e = tid; e < SS * SS; e += 256) {
        int i = e >> 7, j = e & 127;
        float v = simb[e] / (nrmS[i] * nrmS[j]);
        simb[e] = v;
        mn = fminf(mn, v); mx = fmaxf(mx, v);
    }
    __shared__ float rmn[256], rmx[256];
    rmn[tid] = mn; rmx[tid] = mx; __syncthreads();
    for (int o = 128; o > 0; o >>= 1) {
        if (tid < o) { rmn[tid] = fminf(rmn[tid], rmn[tid + o]); rmx[tid] = fmaxf(rmx[tid], rmx[tid + o]); }
        __syncthreads();
    }
    if (tid == 0) { mnmx[0] = rmn[0]; mnmx[1] = rmx[0]; }
}

// ---------- min-max normalize sims in place, deg/dinv ----------
__global__ __launch_bounds__(128) void k_deg(float* __restrict__ simb,
                                             const float* __restrict__ mnmx,
                                             float* __restrict__ deg,
                                             float* __restrict__ dinv) {
    int j = blockIdx.x, i = threadIdx.x;
    float mn = mnmx[0], inv = 1.f / (mnmx[1] - mnmx[0]);
    float s = (simb[i * SS + j] - mn) * inv;
    simb[i * SS + j] = s;
    __shared__ float red[128];
    red[i] = s; __syncthreads();
    for (int o = 64; o > 0; o >>= 1) { if (i < o) red[i] += red[i + o]; __syncthreads(); }
    if (i == 0) { float d = red[0] + 1.f; deg[j] = d; dinv[j] = rsqrtf(d); }
}

// ---------- GCN neighbor aggregate (j<128), grid (SS,3) ----------
__global__ __launch_bounds__(256) void k_agg(const float* __restrict__ simb,
                                             const float* __restrict__ dinv,
                                             const uint16_t* __restrict__ xw,
                                             float* __restrict__ aggb) {
    int j = blockIdx.x;
    int d = blockIdx.y * 256 + threadIdx.x;
    __shared__ float w[SS];
    if (threadIdx.x < SS) w[threadIdx.x] = dinv[threadIdx.x] * simb[threadIdx.x * SS + j] * dinv[j];
    __syncthreads();
    float s = 0.f;
    #pragma unroll 8
    for (int i = 0; i < SS; i++) s += w[i] * b2f(xw[(size_t)i * DD + d]);
    aggb[(size_t)j * DD + d] = s;
}

// ---------- GCN combine in place (vec x8, bf16 state) ----------
__global__ __launch_bounds__(256) void k_gcn_combine(uint16_t* __restrict__ xw,
                                                     const float* __restrict__ aggb,
                                                     const float* __restrict__ deg,
                                                     const void* __restrict__ gcnb,
                                                     const int* __restrict__ flag) {
    uint32_t t = (blockIdx.x * 256 + threadIdx.x) * 8u;   // 4608 blocks, exact
    int isf = flag[0];
    uint32_t n = t / 768u;
    uint32_t d0 = t - n * 768u;
    u16x8 xv = *(const u16x8*)(xw + t);
    float v[8];
    #pragma unroll
    for (int q = 0; q < 8; q++) v[q] = b2f(xv[q]);
    if (n < SS) {
        f32x4 a0 = *(const f32x4*)(aggb + t);
        f32x4 a1 = *(const f32x4*)(aggb + t + 4);
        float dg = deg[n];
        #pragma unroll
        for (int q = 0; q < 4; q++) { v[q] = v[q] / dg + a0[q]; v[q + 4] = v[q + 4] / dg + a1[q]; }
    }
    float bb[8];
    if (isf) {
        f32x4 b0 = *(const f32x4*)((const float*)gcnb + d0);
        f32x4 b1 = *(const f32x4*)((const float*)gcnb + d0 + 4);
        #pragma unroll
        for (int q = 0; q < 4; q++) { bb[q] = b0[q]; bb[q + 4] = b1[q]; }
    } else {
        u16x8 b8 = *(const u16x8*)((const uint16_t*)gcnb + d0);
        #pragma unroll
        for (int q = 0; q < 8; q++) bb[q] = b2f(b8[q]);
    }
    u16x8 ov;
    #pragma unroll
    for (int q = 0; q < 8; q++) ov[q] = f2b(fmaxf(v[q] + bb[q], 0.f));
    *(u16x8*)(xw + t) = ov;
}

// ---------- colsum over first 128 rows (12 blocks, 4-way row split) ----------
// also zeroes mvec (written before any sync; matvec runs strictly after)
__global__ __launch_bounds__(256) void k_colsum(const uint16_t* __restrict__ x,
                                                float* __restrict__ svec,
                                                float* __restrict__ mvec) {
    if (blockIdx.x == 0) {
        mvec[threadIdx.x] = 0.f;
        mvec[threadIdx.x + 256] = 0.f;
        mvec[threadIdx.x + 512] = 0.f;
    }
    int d = blockIdx.x * 64 + (threadIdx.x & 63);
    int part = threadIdx.x >> 6;
    float s = 0.f;
    for (int i = part * 32; i < part * 32 + 32; i++) s += b2f(x[(size_t)i * DD + d]);
    __shared__ float red[256];
    red[threadIdx.x] = s; __syncthreads();
    if (part == 0)
        svec[d] = red[threadIdx.x] + red[threadIdx.x + 64] +
                  red[threadIdx.x + 128] + red[threadIdx.x + 192];
}

// ---------- mvec = svec @ ggc_W[l], d-parallel with atomicAdd ----------
__global__ __launch_bounds__(256) void k_matvec(const float* __restrict__ svec,
                                                const void* __restrict__ Wg, size_t ofs,
                                                float* __restrict__ mvec,
                                                const int* __restrict__ flag) {
    int k = blockIdx.x * 256 + threadIdx.x;
    int d0 = blockIdx.y * 48;
    int isf = flag[0];
    float s = 0.f;
    #pragma unroll 8
    for (int d = d0; d < d0 + 48; d++)
        s += svec[d] * loadf(Wg, ofs + (size_t)d * DD + k, isf);
    atomicAdd(&mvec[k], s);
}

// ---------- giE = mvec @ wih.T + bih ----------
__global__ __launch_bounds__(256) void k_rowdot(const float* __restrict__ mvec,
                                                const void* __restrict__ wih,
                                                const void* __restrict__ bih,
                                                float* __restrict__ giE,
                                                const int* __restrict__ flag) {
    int rr = blockIdx.x, tid = threadIdx.x;
    int isf = flag[0];
    float s = 0.f;
    for (int k = tid; k < DD; k += 256) s += mvec[k] * loadf(wih, (size_t)rr * DD + k, isf);
    __shared__ float red[256];
    red[tid] = s; __syncthreads();
    for (int o = 128; o > 0; o >>= 1) { if (tid < o) red[tid] += red[tid + o]; __syncthreads(); }
    if (tid == 0) giE[rr] = red[0] + loadf(bih, rr, isf);
}

// ---------- y = h_feature + relu(x_g), batched all 3 chunks, vec x8 ----------
__global__ __launch_bounds__(256) void k_build_y(const void* __restrict__ hf,
                                                 const uint16_t* __restrict__ xg,
                                                 uint16_t* __restrict__ y,
                                                 const int* __restrict__ flag) {
    uint32_t t = (blockIdx.x * 256 + threadIdx.x) * 8u;   // 4608 blocks, exact TOTAL_ND
    int isf = flag[0];
    uint32_t u = t;
    if (u >= 2u * NBSD) u -= 2u * NBSD; else if (u >= NBSD) u -= NBSD;
    u16x8 xv = *(const u16x8*)(xg + t);
    float h[8];
    if (isf) {
        f32x4 h0 = *(const f32x4*)((const float*)hf + u);
        f32x4 h1 = *(const f32x4*)((const float*)hf + u + 4);
        #pragma unroll
        for (int q = 0; q < 4; q++) { h[q] = h0[q]; h[q + 4] = h1[q]; }
    } else {
        u16x8 h8 = *(const u16x8*)((const uint16_t*)hf + u);
        #pragma unroll
        for (int q = 0; q < 8; q++) h[q] = b2f(h8[q]);
    }
    u16x8 ov;
    #pragma unroll
    for (int q = 0; q < 8; q++) ov[q] = f2b(h[q] + fmaxf(b2f(xv[q]), 0.f));
    *(u16x8*)(y + t) = ov;
}

// ---------- LayerNorm (batched: 12288 rows, per-g weight select) ----------
__global__ __launch_bounds__(256) void k_ln(const uint16_t* __restrict__ tin,
                                            const void* g0, const void* b0,
                                            const void* g1, const void* b1,
                                            const void* g2, const void* b2,
                                            float* __restrict__ out,
                                            const int* __restrict__ flag) {
    int m = blockIdx.x, tid = threadIdx.x;
    int isf = flag[0];
    int gs = m >> 12;
    const void* gw = (gs == 0) ? g0 : (gs == 1) ? g1 : g2;
    const void* bw = (gs == 0) ? b0 : (gs == 1) ? b1 : b2;
    float v0 = b2f(tin[(size_t)m * DD + tid]);
    float v1 = b2f(tin[(size_t)m * DD + tid + 256]);
    float v2 = b2f(tin[(size_t)m * DD + tid + 512]);
    __shared__ float red[256];
    red[tid] = v0 + v1 + v2; __syncthreads();
    for (int o = 128; o > 0; o >>= 1) { if (tid < o) red[tid] += red[tid + o]; __syncthreads(); }
    float mu = red[0] * (1.f / 768.f);
    __syncthreads();
    float d0 = v0 - mu, d1 = v1 - mu, d2 = v2 - mu;
    red[tid] = d0 * d0 + d1 * d1 + d2 * d2; __syncthreads();
    for (int o = 128; o > 0; o >>= 1) { if (tid < o) red[tid] += red[tid + o]; __syncthreads(); }
    float rstd = rsqrtf(red[0] * (1.f / 768.f) + 1e-5f);
    out[(size_t)m * DD + tid]       = d0 * rstd * loadf(gw, tid, isf)       + loadf(bw, tid, isf);
    out[(size_t)m * DD + tid + 256] = d1 * rstd * loadf(gw, tid + 256, isf) + loadf(bw, tid + 256, isf);
    out[(size_t)m * DD + tid + 512] = d2 * rstd * loadf(gw, tid + 512, isf) + loadf(bw, tid + 512, isf);
}

// ---------- weight convert: hi-only bf16, elementwise vec x4 (whh) ----------
__global__ __launch_bounds__(256) void k_cvt1(const void* __restrict__ src,
                                              uint16_t* __restrict__ dh, int n,
                                              const int* __restrict__ flag) {
    int t = (blockIdx.x * 256 + threadIdx.x) * 4;   // exact cover
    int isf = flag[0];
    u16x4 hh;
    if (isf) {
        f32x4 s = *(const f32x4*)((const float*)src + t);
        #pragma unroll
        for (int q = 0; q < 4; q++) hh[q] = f2b(s[q]);
    } else {
        hh = *(const u16x4*)((const uint16_t*)src + t);
    }
    *(u16x4*)(dh + t) = hh;
}

// ---------- weight convert: transpose + hi/lo split, 7 matrices batched ----------
__global__ __launch_bounds__(256) void k_cvtT7(const void* s0, const void* s1,
                                               const void* s2, const void* s3,
                                               const void* s4, const void* s5,
                                               const void* s6,
                                               uint16_t* __restrict__ gdst,
                                               uint16_t* __restrict__ tail,
                                               const int* __restrict__ flag) {
    __shared__ float tile[64][65];
    int isf = flag[0];
    int z = blockIdx.z;
    const void* src = (z == 0) ? s0 : (z == 1) ? s1 : (z == 2) ? s2 :
                      (z == 3) ? s3 : (z == 4) ? s4 : (z == 5) ? s5 : s6;
    uint16_t* dh = (z == 0) ? gdst : tail + (size_t)(z - 1) * WSLOT;
    uint16_t* dl = dh + WMAT;
    int k0 = blockIdx.x * 64, n0 = blockIdx.y * 64;
    for (int t = threadIdx.x; t < 4096; t += 256) {
        int r = t >> 6, c = t & 63;
        tile[r][c] = loadf(src, (size_t)(k0 + r) * DD + n0 + c, isf);
    }
    __syncthreads();
    for (int base = 0; base < 4096; base += 512) {
        int t = base + threadIdx.x * 2;
        int r = t >> 6, c = t & 63;
        float va = tile[c][r], vb = tile[c + 1][r];
        uint16_t ha = f2b(va), hb = f2b(vb);
        size_t o = (size_t)(n0 + r) * DD + k0 + c;
        *(u16x2*)(dh + o) = (u16x2){ha, hb};
        *(u16x2*)(dl + o) = (u16x2){f2b(va - b2f(ha)), f2b(vb - b2f(hb))};
    }
}

// =============== MFMA GEMM: C[M,768] = A[M,768] @ BT^T ====
// 128x128 tile, BK=32, 8 waves (512 thr): per-wave 32x64, acc=32 floats.
// LO: use lo-residual B pass (only when input fp32). DB: 2-phase double buffer.
enum { EPI_NONE = 0, EPI_BIAS_RELU = 3, EPI_BIAS = 4 };

template<int EPI, int ISF, int LO, int DB>
__device__ __forceinline__ void mgemm_core(
    const uint16_t* __restrict__ Az, const uint16_t* __restrict__ Bh,
    const uint16_t* __restrict__ Bl, const void* bias,
    uint16_t* __restrict__ Cz, uint16_t* As, uint16_t* Bs, int m0, int n0) {
    const int tid = threadIdx.x, lane = tid & 63;
    const int wid = tid >> 6;                  // 0..7
    const int wr = wid >> 1, wc = wid & 1;     // 4 M-quads x 2 N-halves
    constexpr int UL = (ISF && LO);            // use lo pass
    constexpr int BSZ = UL ? 8192 : 4096;      // per-buffer B size (u16)

    f32x4 acc[2][4];
    #pragma unroll
    for (int i = 0; i < 2; i++)
        #pragma unroll
        for (int j = 0; j < 4; j++) acc[i][j] = (f32x4){0.f, 0.f, 0.f, 0.f};

    // staging indices: 512 chunks of 16B cover a 128x32 tile (4 groups/row)
    const int scr = tid >> 2;                              // row 0..127
    const int sgl = (tid & 3) ^ ((scr >> 1) & 3);          // swizzled group
    const int sdst = tid * 8;

    int offA[2], offB[4];
    #pragma unroll
    for (int i = 0; i < 2; i++) {
        int r = wr * 32 + i * 16 + (lane & 15);
        offA[i] = r * 32 + (((lane >> 4) ^ ((r >> 1) & 3)) << 3);
    }
    #pragma unroll
    for (int j = 0; j < 4; j++) {
        int r = wc * 64 + j * 16 + (lane & 15);
        offB[j] = r * 32 + (((lane >> 4) ^ ((r >> 1) & 3)) << 3);
    }

    auto STAGE = [&](int buf, int k0) {
        gload16(Az + (size_t)(m0 + scr) * DD + k0 + sgl * 8, As + buf * 4096 + sdst);
        gload16(Bh + (size_t)(n0 + scr) * DD + k0 + sgl * 8, Bs + buf * BSZ + sdst);
        if (UL) gload16(Bl + (size_t)(n0 + scr) * DD + k0 + sgl * 8,
                        Bs + buf * BSZ + 4096 + sdst);
    };
    auto COMPUTE = [&](const uint16_t* Ac, const uint16_t* Bc) {
        bf16x8 af[2], b4[4], l4[4];
        #pragma unroll
        for (int i = 0; i < 2; i++) af[i] = *(const bf16x8*)(Ac + offA[i]);
        #pragma unroll
        for (int j = 0; j < 4; j++) {
            b4[j] = *(const bf16x8*)(Bc + offB[j]);
            if (UL) l4[j] = *(const bf16x8*)(Bc + 4096 + offB[j]);
        }
        #pragma unroll
        for (int i = 0; i < 2; i++)
            #pragma unroll
            for (int j = 0; j < 4; j++)
                acc[i][j] = __builtin_amdgcn_mfma_f32_16x16x32_bf16(af[i], b4[j], acc[i][j], 0, 0, 0);
        if (UL) {
            #pragma unroll
            for (int i = 0; i < 2; i++)
                #pragma unroll
                for (int j = 0; j < 4; j++)
                    acc[i][j] = __builtin_amdgcn_mfma_f32_16x16x32_bf16(af[i], l4[j], acc[i][j], 0, 0, 0);
        }
    };

    if (DB) {
        STAGE(0, 0);
        __syncthreads();
        int buf = 0;
        for (int t = 0; t < 24; ++t) {
            if (t < 23) STAGE(buf ^ 1, (t + 1) * 32);
            COMPUTE(As + buf * 4096, Bs + buf * BSZ);
            __syncthreads();
            buf ^= 1;
        }
    } else {
        for (int k0 = 0; k0 < DD; k0 += 32) {
            STAGE(0, k0);
            __syncthreads();
            COMPUTE(As, Bs);
            __syncthreads();
        }
    }
    // D layout: col = lane&15, row = (lane>>4)*4 + q
    #pragma unroll
    for (int i = 0; i < 2; i++) {
        #pragma unroll
        for (int j = 0; j < 4; j++) {
            int n = n0 + wc * 64 + j * 16 + (lane & 15);
            int mb = m0 + wr * 32 + i * 16 + ((lane >> 4) << 2);
            float bv = 0.f;
            if (EPI != EPI_NONE) bv = loadf(bias, n, ISF);
            #pragma unroll
            for (int q = 0; q < 4; q++) {
                float v = acc[i][j][q];
                if (EPI == EPI_BIAS_RELU) v = fmaxf(v + bv, 0.f);
                else if (EPI == EPI_BIAS) v = v + bv;
                Cz[(size_t)(mb + q) * DD + n] = f2b(v);
            }
        }
    }
}

template<int EPI, int LO, int DB>
__global__ __launch_bounds__(512, 4)
void k_mgemm(const uint16_t* __restrict__ A, uint32_t aZ,
             const uint16_t* __restrict__ BTh, uint32_t bZ,
             const void* bias0, const void* bias1, const void* bias2,
             uint16_t* __restrict__ C, uint32_t cZ,
             const int* __restrict__ flag) {
    __shared__ __align__(16) uint16_t As[(DB ? 2 : 1) * 4096];
    __shared__ __align__(16) uint16_t Bs[(DB ? 2 : 1) * (LO ? 2 : 1) * 4096];
    const int isf = flag[0];
    const int z = blockIdx.z;
    const uint16_t* Az = A + (size_t)z * aZ;
    const uint16_t* Bh = BTh + (size_t)z * bZ;
    const uint16_t* Bl = Bh + WMAT;
    uint16_t* Cz = C + (size_t)z * cZ;
    const void* bias = (z == 0) ? bias0 : (z == 1) ? bias1 : bias2;
    const int m0 = blockIdx.y * 128, n0 = blockIdx.x * 128;
    if (isf) mgemm_core<EPI, 1, LO, DB>(Az, Bh, Bl, bias, Cz, As, Bs, m0, n0);
    else     mgemm_core<EPI, 0, LO, DB>(Az, Bh, Bl, bias, Cz, As, Bs, m0, n0);
}

// =============== MFMA fused GRU layer: 3-gate GEMM (whh hi-only) + cell ====
// Tile M=128 x (3 gates x 64), 8 waves (512 thr): per-wave 32M x 32N/gate.
// 2-phase double-buffered staging (40KB LDS, 4 blocks/CU maintained).
template<int ISF>
__device__ __forceinline__ void grum_core(
    const uint16_t* __restrict__ X,
    const uint16_t* __restrict__ Wh,
    const void* __restrict__ bih, const void* __restrict__ bhh,
    const float* __restrict__ giE, uint16_t* __restrict__ Xn,
    uint16_t* As, uint16_t* Bs, int m0, int n0) {
    const int tid = threadIdx.x, lane = tid & 63;
    const int wid = tid >> 6;                  // 0..7
    const int wr = wid >> 1, wc = wid & 1;     // 4 M-quads x 2 N-halves

    f32x4 acc[3][2][2];
    #pragma unroll
    for (int gg = 0; gg < 3; gg++)
        #pragma unroll
        for (int i = 0; i < 2; i++)
            #pragma unroll
            for (int j = 0; j < 2; j++) acc[gg][i][j] = (f32x4){0.f, 0.f, 0.f, 0.f};

    // A staging: 512 chunks cover 128x32
    const int acr = tid >> 2;
    const int agl = (tid & 3) ^ ((acr >> 1) & 3);
    // B staging: threads 0..255 stage 3 gates (hi only), 256 chunks per gate
    const int bc = tid & 255;
    const int bcr = bc >> 2;
    const int bgl = (bc & 3) ^ ((bcr >> 1) & 3);

    int offA[2], offB[2];
    #pragma unroll
    for (int i = 0; i < 2; i++) {
        int r = wr * 32 + i * 16 + (lane & 15);
        offA[i] = r * 32 + (((lane >> 4) ^ ((r >> 1) & 3)) << 3);
    }
    #pragma unroll
    for (int j = 0; j < 2; j++) {
        int r = wc * 32 + j * 16 + (lane & 15);
        offB[j] = r * 32 + (((lane >> 4) ^ ((r >> 1) & 3)) << 3);
    }

    auto STAGE = [&](int buf, int k0) {
        gload16(X + (size_t)(m0 + acr) * DD + k0 + agl * 8, As + buf * 4096 + tid * 8);
        if (tid < 256) {
            #pragma unroll
            for (int gg = 0; gg < 3; gg++)
                gload16(Wh + (size_t)(gg * DD + n0 + bcr) * DD + k0 + bgl * 8,
                        Bs + buf * 6144 + gg * 2048 + bc * 8);
        }
    };
    auto COMPUTE = [&](const uint16_t* Ac, const uint16_t* Bc) {
        bf16x8 af[2];
        #pragma unroll
        for (int i = 0; i < 2; i++) af[i] = *(const bf16x8*)(Ac + offA[i]);
        #pragma unroll
        for (int gg = 0; gg < 3; gg++) {
            const uint16_t* Bhc = Bc + gg * 2048;
            bf16x8 bh2[2];
            #pragma unroll
            for (int j = 0; j < 2; j++) bh2[j] = *(const bf16x8*)(Bhc + offB[j]);
            #pragma unroll
            for (int j = 0; j < 2; j++)
                #pragma unroll
                for (int i = 0; i < 2; i++)
                    acc[gg][i][j] = __builtin_amdgcn_mfma_f32_16x16x32_bf16(af[i], bh2[j], acc[gg][i][j], 0, 0, 0);
        }
    };

    STAGE(0, 0);
    __syncthreads();
    int buf = 0;
    for (int t = 0; t < 24; ++t) {
        if (t < 23) STAGE(buf ^ 1, (t + 1) * 32);
        COMPUTE(As + buf * 4096, Bs + buf * 6144);
        __syncthreads();
        buf ^= 1;
    }
    // epilogue: full GRU cell pointwise
    #pragma unroll
    for (int j = 0; j < 2; j++) {
        int n = n0 + wc * 32 + j * 16 + (lane & 15);
        float bh0 = loadf(bhh, n, ISF);
        float bh1 = loadf(bhh, DD + n, ISF);
        float bh2v = loadf(bhh, 2 * DD + n, ISF);
        float gE0 = giE[n], gE1 = giE[DD + n], gE2 = giE[2 * DD + n];
        float bi0 = loadf(bih, n, ISF);
        float bi1 = loadf(bih, DD + n, ISF);
        float bi2 = loadf(bih, 2 * DD + n, ISF);
        #pragma unroll
        for (int i = 0; i < 2; i++) {
            int mb = m0 + wr * 32 + i * 16 + ((lane >> 4) << 2);
            #pragma unroll
            for (int q = 0; q < 4; q++) {
                int m = mb + q;
                bool msg = (m < SS);
                float gr = msg ? gE0 : bi0;
                float gz = msg ? gE1 : bi1;
                float gn = msg ? gE2 : bi2;
                float rg = 1.f / (1.f + expf(-(acc[0][i][j][q] + bh0 + gr)));
                float zg = 1.f / (1.f + expf(-(acc[1][i][j][q] + bh1 + gz)));
                float hn = acc[2][i][j][q] + bh2v;
                float nn = tanhf(gn + rg * hn);
                float xo = b2f(X[(size_t)m * DD + n]);
                Xn[(size_t)m * DD + n] = f2b((1.f - zg) * nn + zg * xo);
            }
        }
    }
}

__global__ __launch_bounds__(512, 4)
void k_grum(const uint16_t* __restrict__ X,
            const uint16_t* __restrict__ Wh,
            const void* __restrict__ bih, const void* __restrict__ bhh,
            const float* __restrict__ giE, uint16_t* __restrict__ Xn,
            const int* __restrict__ flag) {
    __shared__ __align__(16) uint16_t As[2 * 4096];      // dbuf 128x32 (16KB)
    __shared__ __align__(16) uint16_t Bs[2 * 3 * 2048];  // dbuf 3 gates x 64x32 (24KB)
    const int n0 = blockIdx.x * 64, m0 = blockIdx.y * 128;
    if (flag[0]) grum_core<1>(X, Wh, bih, bhh, giE, Xn, As, Bs, m0, n0);
    else         grum_core<0>(X, Wh, bih, bhh, giE, Xn, As, Bs, m0, n0);
}

// ============================== driver ==============================
extern "C" void kernel_launch(void* const* d_in, const int* in_sizes, int n_in,
                              void* d_out, int out_size, void* d_ws, size_t ws_size,
                              hipStream_t stream) {
    float* OUTF = (float*)d_out;            // FINAL output: fp32
    uint16_t* OB = (uint16_t*)d_out;        // first 18.9MB of d_out as bf16 trunk/H scratch

    static const int expect[29] = {
        3145728,3145728,3145728,3145728, 589824,768, 1179648, 1769472,1769472, 2304,2304,
        589824,768,589824,768,768,768,
        589824,768,589824,768,768,768,
        589824,768,589824,768,768,768 };
    int bad = -1;
    if (n_in != 29) bad = 90;
    else { for (int i = 0; i < 29; i++) if (in_sizes[i] != expect[i]) { bad = i; break; } }
    if (bad < 0 && out_size != (int)TOTAL_ND) bad = 91;
    if (bad < 0 && ws_size < 33ull * 1024 * 1024) bad = 92;
    if (bad >= 0) {
        k_diag<<<1, 64, 0, stream>>>(OUTF, 10000.f + 100.f * (float)bad);
        return;
    }

    // ws layout (floats): small scratch | F128 hi/lo | W0 | WH | WT  (~30.8 MiB)
    float* fbase = (float*)d_ws;
    float* simb = fbase;                        // 16384
    float* mnmx = simb + 16384;                 // 2
    float* deg  = mnmx + 2;                     // 128
    float* dinv = deg + 128;                    // 128
    float* aggb = dinv + 128;                   // 98304
    float* svec = aggb + 98304;                 // 768
    float* mvec = svec + 768;                   // 768
    float* giE  = mvec + 768;                   // 2304
    int*   flag = (int*)(giE + 2304);           // 1
    uint16_t* F128h = (uint16_t*)(fbase + 118916);  // 98304 u16
    uint16_t* F128l = (uint16_t*)(fbase + 168068);  // 98304 u16
    uint16_t* W0 = (uint16_t*)(fbase + 217220);     // 9,437,184 u16
    uint16_t* WH = W0 + TOTAL_ND;                   // 3,145,728 u16 slots
    uint16_t* WT = WH + NBSD;                       // 3,145,728 u16 slots (spare)

    // head weights hi/lo live in the TAIL of d_out (last 13.5 MB; dead before LN)
    uint16_t* tailW = (uint16_t*)((char*)d_out + 23592960);  // 6 slots x WSLOT

    const void* hf = d_in[0];
    const void* hc = d_in[1];
    const void* hd = d_in[2];
    const void* hs = d_in[3];

    k_probe<<<1, 64, 0, stream>>>(hf, flag);

    // ---- all transpose-weight conversions batched (gcn_W -> WH, heads -> tail) ----
    k_cvtT7<<<dim3(12, 12, 7), 256, 0, stream>>>(
        d_in[4], d_in[11], d_in[13], d_in[17], d_in[19], d_in[23], d_in[25],
        WH, tailW, flag);

    // ---- GCN front-end ----
    k_build_all<<<3456, 256, 0, stream>>>(hc, hd, hs, W0, F128h, F128l, flag);
    k_simgemm<<<dim3(2, 2), 256, 0, stream>>>(F128h, F128l, simb);
    k_simpost<<<1, 256, 0, stream>>>(simb, mnmx);
    k_deg<<<SS, SS, 0, stream>>>(simb, mnmx, deg, dinv);
    // trunk xw GEMM: gcn_W hi-only (LO=0), double-buffered (DB=1)
    k_mgemm<EPI_NONE, 0, 1><<<dim3(6, 96, 1), 512, 0, stream>>>(
        W0, 0, WH, 0, nullptr, nullptr, nullptr, OB, 0, flag);
    k_agg<<<dim3(SS, 3), 256, 0, stream>>>(simb, dinv, OB, aggb);
    k_gcn_combine<<<4608, 256, 0, stream>>>(OB, aggb, deg, d_in[5], flag);

    // ---- GatedGraphConv: whh -> WH bf16 hi only (gcn_W in WH now dead) ----
    k_cvt1<<<1728, 256, 0, stream>>>(d_in[8], WH, 1769472, flag);

    k_colsum<<<12, 256, 0, stream>>>(OB, svec, mvec);
    k_matvec<<<dim3(3, 16), 256, 0, stream>>>(svec, d_in[6], 0, mvec, flag);
    k_rowdot<<<2304, 256, 0, stream>>>(mvec, d_in[7], d_in[9], giE, flag);
    k_grum<<<dim3(12, 96), 512, 0, stream>>>(OB, WH, d_in[9], d_in[10], giE, W0, flag);

    k_colsum<<<12, 256, 0, stream>>>(W0, svec, mvec);
    k_matvec<<<dim3(3, 16), 256, 0, stream>>>(svec, d_in[6], (size_t)DD * DD, mvec, flag);
    k_rowdot<<<2304, 256, 0, stream>>>(mvec, d_in[7], d_in[9], giE, flag);
    k_grum<<<dim3(12, 96), 512, 0, stream>>>(W0, WH, d_in[9], d_in[10], giE, OB, flag);

    // ---- y = hf + relu(x) for all 3 chunks (OB -> W0); OB then dead ----
    k_build_y<<<4608, 256, 0, stream>>>(hf, OB, W0, flag);

    // ---- heads batched over z: y(W0) -> H(OB) -> T(W0) -> LN(d_out) ----
    k_mgemm<EPI_BIAS_RELU, 1, 0><<<dim3(6, 32, 3), 512, 0, stream>>>(
        W0, NBSD, tailW, 2 * WSLOT, d_in[12], d_in[18], d_in[24], OB, NBSD, flag);
    k_mgemm<EPI_BIAS, 1, 0><<<dim3(6, 32, 3), 512, 0, stream>>>(
        OB, NBSD, tailW + WSLOT, 2 * WSLOT, d_in[14], d_in[20], d_in[26], W0, NBSD, flag);
    k_ln<<<NNODE, 256, 0, stream>>>(W0, d_in[15], d_in[16], d_in[21], d_in[22],
                                    d_in[27], d_in[28], OUTF, flag);
}

// Round 11
// 601.370 us; speedup vs baseline: 1.6699x; 1.0427x over previous
//
#include <hip/hip_runtime.h>
#include <cstdint>
#include <cstddef>

#define DD 768
#define SS 128
#define NNODE 12288            // 3*B*S
#define NBS 4096               // B*S
#define NBSD 3145728           // B*S*D (per-chunk elements)
#define TOTAL_ND 9437184ULL    // NNODE*DD == out_size (fp32 elements)
#define WMAT 589824            // 768*768
#define WSLOT 1179648          // slot stride of one converted 768x768 matrix (u16)

typedef __attribute__((ext_vector_type(4))) float f32x4;
typedef __attribute__((ext_vector_type(8))) short bf16x8;
typedef __attribute__((ext_vector_type(4))) uint16_t u16x4;
typedef __attribute__((ext_vector_type(2))) uint16_t u16x2;
typedef __attribute__((ext_vector_type(8))) uint16_t u16x8;
typedef __attribute__((ext_vector_type(2))) uint32_t u32x2;

__device__ __forceinline__ float b2f(uint16_t u) {
    union { uint32_t i; float f; } x; x.i = ((uint32_t)u) << 16; return x.f;
}
__device__ __forceinline__ uint16_t f2b(float f) {
    uint32_t x = __float_as_uint(f);
    return (uint16_t)((x + 0x7FFFu + ((x >> 16) & 1u)) >> 16);
}
__device__ __forceinline__ float loadf(const void* p, size_t i, int isf32) {
    return isf32 ? ((const float*)p)[i] : b2f(((const uint16_t*)p)[i]);
}
// feats[n][d] = src_{d%3}[n*256 + d/3]
__device__ __forceinline__ float featAt(const void* hc, const void* hd, const void* hs,
                                        int n, int d, int isf) {
    int w = d % 3;
    size_t u = (size_t)n * 256 + (size_t)(d / 3);
    const void* p = (w == 0) ? hc : (w == 1) ? hd : hs;
    return loadf(p, u, isf);
}
__device__ __forceinline__ uint32_t pk2(uint16_t a, uint16_t b) {
    return (uint32_t)a | ((uint32_t)b << 16);
}

// async 16B global->LDS (linear dest: wave-uniform base + lane*16)
__device__ __forceinline__ void gload16(const uint16_t* g, uint16_t* l) {
    __builtin_amdgcn_global_load_lds(
        (__attribute__((address_space(1))) uint32_t*)(uintptr_t)g,
        (__attribute__((address_space(3))) uint32_t*)l, 16, 0, 0);
}

// ---------- diag beacon ----------
__global__ void k_diag(float* out, float code) {
    if (threadIdx.x == 0 && blockIdx.x == 0) out[0] = code;
}

// ---------- dtype probe ----------
__global__ void k_probe(const void* hf, int* flag) {
    if (threadIdx.x == 0 && blockIdx.x == 0) {
        const uint32_t* w = (const uint32_t*)hf;
        int bad = 0;
        for (int k = 0; k < 64; k++) {
            uint16_t lo = (uint16_t)(w[k] & 0xFFFFu);
            int e = (lo >> 7) & 0xFF;
            if (e < 100 || e > 140) bad++;
        }
        flag[0] = (bad > 24) ? 1 : 0;
    }
}

// ---------- feats build + F128 hi/lo split (merged) ----------
__global__ __launch_bounds__(256) void k_build_all(
    const void* __restrict__ hc, const void* __restrict__ hd,
    const void* __restrict__ hs, uint16_t* __restrict__ feats,
    uint16_t* __restrict__ Fh, uint16_t* __restrict__ Fl,
    const int* __restrict__ flag) {
    int isf = flag[0];
    if (blockIdx.x < 3072) {
        int u = (blockIdx.x * 256 + threadIdx.x) * 4;
        float a[4], b[4], c[4];
        if (isf) {
            f32x4 va = *(const f32x4*)((const float*)hc + u);
            f32x4 vb = *(const f32x4*)((const float*)hd + u);
            f32x4 vc = *(const f32x4*)((const float*)hs + u);
            #pragma unroll
            for (int q = 0; q < 4; q++) { a[q] = va[q]; b[q] = vb[q]; c[q] = vc[q]; }
        } else {
            u16x4 va = *(const u16x4*)((const uint16_t*)hc + u);
            u16x4 vb = *(const u16x4*)((const uint16_t*)hd + u);
            u16x4 vc = *(const u16x4*)((const uint16_t*)hs + u);
            #pragma unroll
            for (int q = 0; q < 4; q++) { a[q] = b2f(va[q]); b[q] = b2f(vb[q]); c[q] = b2f(vc[q]); }
        }
        uint16_t o[12];
        #pragma unroll
        for (int q = 0; q < 4; q++) {
            o[3 * q] = f2b(a[q]); o[3 * q + 1] = f2b(b[q]); o[3 * q + 2] = f2b(c[q]);
        }
        u32x2 w0 = {pk2(o[0], o[1]), pk2(o[2], o[3])};
        u32x2 w1 = {pk2(o[4], o[5]), pk2(o[6], o[7])};
        u32x2 w2 = {pk2(o[8], o[9]), pk2(o[10], o[11])};
        *(u32x2*)(feats + (size_t)3 * u) = w0;
        *(u32x2*)(feats + (size_t)3 * u + 4) = w1;
        *(u32x2*)(feats + (size_t)3 * u + 8) = w2;
    } else {
        int t = (blockIdx.x - 3072) * 256 + threadIdx.x;   // 384 blocks -> 98304
        int n = t / DD, d = t - n * DD;
        float v = featAt(hc, hd, hs, n, d, isf);
        uint16_t h = f2b(v);
        Fh[t] = h;
        Fl[t] = f2b(v - b2f(h));
    }
}

// ---------- G = F F^T via MFMA hi/lo (drops ll term, ~1e-5 rel err) ----------
__global__ __launch_bounds__(256)
void k_simgemm(const uint16_t* __restrict__ Fh, const uint16_t* __restrict__ Fl,
               float* __restrict__ G) {
    __shared__ __align__(16) uint16_t Ah[64 * 32], Al[64 * 32], Bh_[64 * 32], Bl_[64 * 32];
    const int tid = threadIdx.x, lane = tid & 63, wid = tid >> 6;
    const int wr = wid >> 1, wc = wid & 1;
    const int m0 = blockIdx.y * 64, n0 = blockIdx.x * 64;
    f32x4 acc[2][2];
    #pragma unroll
    for (int i = 0; i < 2; i++)
        #pragma unroll
        for (int j = 0; j < 2; j++) acc[i][j] = (f32x4){0.f, 0.f, 0.f, 0.f};
    const int sr = tid >> 2, sg = tid & 3;
    const int sgl = sg ^ ((sr >> 1) & 3);
    const int dofs = wid * 64 * 8;
    for (int k0 = 0; k0 < DD; k0 += 32) {
        gload16(Fh + (size_t)(m0 + sr) * DD + k0 + sgl * 8, Ah + dofs);
        gload16(Fl + (size_t)(m0 + sr) * DD + k0 + sgl * 8, Al + dofs);
        gload16(Fh + (size_t)(n0 + sr) * DD + k0 + sgl * 8, Bh_ + dofs);
        gload16(Fl + (size_t)(n0 + sr) * DD + k0 + sgl * 8, Bl_ + dofs);
        __syncthreads();
        bf16x8 ah[2], al[2], bh2[2], bl2[2];
        #pragma unroll
        for (int i = 0; i < 2; i++) {
            int r = wr * 32 + i * 16 + (lane & 15);
            int g = (lane >> 4) ^ ((r >> 1) & 3);
            ah[i] = *(const bf16x8*)(Ah + r * 32 + g * 8);
            al[i] = *(const bf16x8*)(Al + r * 32 + g * 8);
        }
        #pragma unroll
        for (int j = 0; j < 2; j++) {
            int r = wc * 32 + j * 16 + (lane & 15);
            int g = (lane >> 4) ^ ((r >> 1) & 3);
            bh2[j] = *(const bf16x8*)(Bh_ + r * 32 + g * 8);
            bl2[j] = *(const bf16x8*)(Bl_ + r * 32 + g * 8);
        }
        #pragma unroll
        for (int i = 0; i < 2; i++)
            #pragma unroll
            for (int j = 0; j < 2; j++)
                acc[i][j] = __builtin_amdgcn_mfma_f32_16x16x32_bf16(ah[i], bh2[j], acc[i][j], 0, 0, 0);
        #pragma unroll
        for (int i = 0; i < 2; i++)
            #pragma unroll
            for (int j = 0; j < 2; j++)
                acc[i][j] = __builtin_amdgcn_mfma_f32_16x16x32_bf16(ah[i], bl2[j], acc[i][j], 0, 0, 0);
        #pragma unroll
        for (int i = 0; i < 2; i++)
            #pragma unroll
            for (int j = 0; j < 2; j++)
                acc[i][j] = __builtin_amdgcn_mfma_f32_16x16x32_bf16(al[i], bh2[j], acc[i][j], 0, 0, 0);
        __syncthreads();
    }
    #pragma unroll
    for (int i = 0; i < 2; i++)
        #pragma unroll
        for (int j = 0; j < 2; j++) {
            int n = n0 + wc * 32 + j * 16 + (lane & 15);
            int mb = m0 + wr * 32 + i * 16 + ((lane >> 4) << 2);
            #pragma unroll
            for (int q = 0; q < 4; q++)
                G[(size_t)(mb + q) * SS + n] = acc[i][j][q];
        }
}

// ---------- sim post: nrm from diag -> cos normalize (in place) -> minmax ----------
__global__ __launch_bounds__(256) void k_simpost(float* __restrict__ simb,
                                                 float* __restrict__ mnmx) {
    int tid = threadIdx.x;
    __shared__ float nrmS[SS];
    if (tid < SS) nrmS[tid] = fmaxf(sqrtf(simb[(size_t)tid * SS + tid]), 1e-8f);
    __syncthreads();
    float mn = 3.4e38f, mx = -3.4e38f;
    for (int e = tid; e < SS * SS; e += 256) {
        int i = e >> 7, j = e & 127;
        float v = simb[e] / (nrmS[i] * nrmS[j]);
        simb[e] = v;
        mn = fminf(mn, v); mx = fmaxf(mx, v);
    }
    __shared__ float rmn[256], rmx[256];
    rmn[tid] = mn; rmx[tid] = mx; __syncthreads();
    for (int o = 128; o > 0; o >>= 1) {
        if (tid < o) { rmn[tid] = fminf(rmn[tid], rmn[tid + o]); rmx[tid] = fmaxf(rmx[tid], rmx[tid + o]); }
        __syncthreads();
    }
    if (tid == 0) { mnmx[0] = rmn[0]; mnmx[1] = rmx[0]; }
}

// ---------- min-max normalize sims in place, deg/dinv ----------
__global__ __launch_bounds__(128) void k_deg(float* __restrict__ simb,
                                             const float* __restrict__ mnmx,
                                             float* __restrict__ deg,
                                             float* __restrict__ dinv) {
    int j = blockIdx.x, i = threadIdx.x;
    float mn = mnmx[0], inv = 1.f / (mnmx[1] - mnmx[0]);
    float s = (simb[i * SS + j] - mn) * inv;
    simb[i * SS + j] = s;
    __shared__ float red[128];
    red[i] = s; __syncthreads();
    for (int o = 64; o > 0; o >>= 1) { if (i < o) red[i] += red[i + o]; __syncthreads(); }
    if (i == 0) { float d = red[0] + 1.f; deg[j] = d; dinv[j] = rsqrtf(d); }
}

// ---------- GCN neighbor aggregate (j<128), grid (SS,3) ----------
__global__ __launch_bounds__(256) void k_agg(const float* __restrict__ simb,
                                             const float* __restrict__ dinv,
                                             const uint16_t* __restrict__ xw,
                                             float* __restrict__ aggb) {
    int j = blockIdx.x;
    int d = blockIdx.y * 256 + threadIdx.x;
    __shared__ float w[SS];
    if (threadIdx.x < SS) w[threadIdx.x] = dinv[threadIdx.x] * simb[threadIdx.x * SS + j] * dinv[j];
    __syncthreads();
    float s = 0.f;
    #pragma unroll 8
    for (int i = 0; i < SS; i++) s += w[i] * b2f(xw[(size_t)i * DD + d]);
    aggb[(size_t)j * DD + d] = s;
}

// ---------- GCN combine in place (vec x8, bf16 state) ----------
__global__ __launch_bounds__(256) void k_gcn_combine(uint16_t* __restrict__ xw,
                                                     const float* __restrict__ aggb,
                                                     const float* __restrict__ deg,
                                                     const void* __restrict__ gcnb,
                                                     const int* __restrict__ flag) {
    uint32_t t = (blockIdx.x * 256 + threadIdx.x) * 8u;   // 4608 blocks, exact
    int isf = flag[0];
    uint32_t n = t / 768u;
    uint32_t d0 = t - n * 768u;
    u16x8 xv = *(const u16x8*)(xw + t);
    float v[8];
    #pragma unroll
    for (int q = 0; q < 8; q++) v[q] = b2f(xv[q]);
    if (n < SS) {
        f32x4 a0 = *(const f32x4*)(aggb + t);
        f32x4 a1 = *(const f32x4*)(aggb + t + 4);
        float dg = deg[n];
        #pragma unroll
        for (int q = 0; q < 4; q++) { v[q] = v[q] / dg + a0[q]; v[q + 4] = v[q + 4] / dg + a1[q]; }
    }
    float bb[8];
    if (isf) {
        f32x4 b0 = *(const f32x4*)((const float*)gcnb + d0);
        f32x4 b1 = *(const f32x4*)((const float*)gcnb + d0 + 4);
        #pragma unroll
        for (int q = 0; q < 4; q++) { bb[q] = b0[q]; bb[q + 4] = b1[q]; }
    } else {
        u16x8 b8 = *(const u16x8*)((const uint16_t*)gcnb + d0);
        #pragma unroll
        for (int q = 0; q < 8; q++) bb[q] = b2f(b8[q]);
    }
    u16x8 ov;
    #pragma unroll
    for (int q = 0; q < 8; q++) ov[q] = f2b(fmaxf(v[q] + bb[q], 0.f));
    *(u16x8*)(xw + t) = ov;
}

// ---------- colsum over first 128 rows (12 blocks, 4-way row split) ----------
// also zeroes mvec (written before any sync; matvec runs strictly after)
__global__ __launch_bounds__(256) void k_colsum(const uint16_t* __restrict__ x,
                                                float* __restrict__ svec,
                                                float* __restrict__ mvec) {
    if (blockIdx.x == 0) {
        mvec[threadIdx.x] = 0.f;
        mvec[threadIdx.x + 256] = 0.f;
        mvec[threadIdx.x + 512] = 0.f;
    }
    int d = blockIdx.x * 64 + (threadIdx.x & 63);
    int part = threadIdx.x >> 6;
    float s = 0.f;
    for (int i = part * 32; i < part * 32 + 32; i++) s += b2f(x[(size_t)i * DD + d]);
    __shared__ float red[256];
    red[threadIdx.x] = s; __syncthreads();
    if (part == 0)
        svec[d] = red[threadIdx.x] + red[threadIdx.x + 64] +
                  red[threadIdx.x + 128] + red[threadIdx.x + 192];
}

// ---------- mvec = svec @ ggc_W[l], d-parallel with atomicAdd ----------
__global__ __launch_bounds__(256) void k_matvec(const float* __restrict__ svec,
                                                const void* __restrict__ Wg, size_t ofs,
                                                float* __restrict__ mvec,
                                                const int* __restrict__ flag) {
    int k = blockIdx.x * 256 + threadIdx.x;
    int d0 = blockIdx.y * 48;
    int isf = flag[0];
    float s = 0.f;
    #pragma unroll 8
    for (int d = d0; d < d0 + 48; d++)
        s += svec[d] * loadf(Wg, ofs + (size_t)d * DD + k, isf);
    atomicAdd(&mvec[k], s);
}

// ---------- giE = mvec @ wih.T + bih ----------
__global__ __launch_bounds__(256) void k_rowdot(const float* __restrict__ mvec,
                                                const void* __restrict__ wih,
                                                const void* __restrict__ bih,
                                                float* __restrict__ giE,
                                                const int* __restrict__ flag) {
    int rr = blockIdx.x, tid = threadIdx.x;
    int isf = flag[0];
    float s = 0.f;
    for (int k = tid; k < DD; k += 256) s += mvec[k] * loadf(wih, (size_t)rr * DD + k, isf);
    __shared__ float red[256];
    red[tid] = s; __syncthreads();
    for (int o = 128; o > 0; o >>= 1) { if (tid < o) red[tid] += red[tid + o]; __syncthreads(); }
    if (tid == 0) giE[rr] = red[0] + loadf(bih, rr, isf);
}

// ---------- y = h_feature + relu(x_g), batched all 3 chunks, vec x8 ----------
__global__ __launch_bounds__(256) void k_build_y(const void* __restrict__ hf,
                                                 const uint16_t* __restrict__ xg,
                                                 uint16_t* __restrict__ y,
                                                 const int* __restrict__ flag) {
    uint32_t t = (blockIdx.x * 256 + threadIdx.x) * 8u;   // 4608 blocks, exact TOTAL_ND
    int isf = flag[0];
    uint32_t u = t;
    if (u >= 2u * NBSD) u -= 2u * NBSD; else if (u >= NBSD) u -= NBSD;
    u16x8 xv = *(const u16x8*)(xg + t);
    float h[8];
    if (isf) {
        f32x4 h0 = *(const f32x4*)((const float*)hf + u);
        f32x4 h1 = *(const f32x4*)((const float*)hf + u + 4);
        #pragma unroll
        for (int q = 0; q < 4; q++) { h[q] = h0[q]; h[q + 4] = h1[q]; }
    } else {
        u16x8 h8 = *(const u16x8*)((const uint16_t*)hf + u);
        #pragma unroll
        for (int q = 0; q < 8; q++) h[q] = b2f(h8[q]);
    }
    u16x8 ov;
    #pragma unroll
    for (int q = 0; q < 8; q++) ov[q] = f2b(h[q] + fmaxf(b2f(xv[q]), 0.f));
    *(u16x8*)(y + t) = ov;
}

// ---------- LayerNorm (batched: 12288 rows, per-g weight select) ----------
__global__ __launch_bounds__(256) void k_ln(const uint16_t* __restrict__ tin,
                                            const void* g0, const void* b0,
                                            const void* g1, const void* b1,
                                            const void* g2, const void* b2,
                                            float* __restrict__ out,
                                            const int* __restrict__ flag) {
    int m = blockIdx.x, tid = threadIdx.x;
    int isf = flag[0];
    int gs = m >> 12;
    const void* gw = (gs == 0) ? g0 : (gs == 1) ? g1 : g2;
    const void* bw = (gs == 0) ? b0 : (gs == 1) ? b1 : b2;
    float v0 = b2f(tin[(size_t)m * DD + tid]);
    float v1 = b2f(tin[(size_t)m * DD + tid + 256]);
    float v2 = b2f(tin[(size_t)m * DD + tid + 512]);
    __shared__ float red[256];
    red[tid] = v0 + v1 + v2; __syncthreads();
    for (int o = 128; o > 0; o >>= 1) { if (tid < o) red[tid] += red[tid + o]; __syncthreads(); }
    float mu = red[0] * (1.f / 768.f);
    __syncthreads();
    float d0 = v0 - mu, d1 = v1 - mu, d2 = v2 - mu;
    red[tid] = d0 * d0 + d1 * d1 + d2 * d2; __syncthreads();
    for (int o = 128; o > 0; o >>= 1) { if (tid < o) red[tid] += red[tid + o]; __syncthreads(); }
    float rstd = rsqrtf(red[0] * (1.f / 768.f) + 1e-5f);
    out[(size_t)m * DD + tid]       = d0 * rstd * loadf(gw, tid, isf)       + loadf(bw, tid, isf);
    out[(size_t)m * DD + tid + 256] = d1 * rstd * loadf(gw, tid + 256, isf) + loadf(bw, tid + 256, isf);
    out[(size_t)m * DD + tid + 512] = d2 * rstd * loadf(gw, tid + 512, isf) + loadf(bw, tid + 512, isf);
}

// ---------- weight convert: hi-only bf16, elementwise vec x4 (whh) ----------
__global__ __launch_bounds__(256) void k_cvt1(const void* __restrict__ src,
                                              uint16_t* __restrict__ dh, int n,
                                              const int* __restrict__ flag) {
    int t = (blockIdx.x * 256 + threadIdx.x) * 4;   // exact cover
    int isf = flag[0];
    u16x4 hh;
    if (isf) {
        f32x4 s = *(const f32x4*)((const float*)src + t);
        #pragma unroll
        for (int q = 0; q < 4; q++) hh[q] = f2b(s[q]);
    } else {
        hh = *(const u16x4*)((const uint16_t*)src + t);
    }
    *(u16x4*)(dh + t) = hh;
}

// ---------- weight convert: transpose + bf16 (hi only), 7 matrices batched ----------
// No lo-residual consumer remains (all GEMMs hi-only except simgemm, which has
// its own F128 hi/lo path), so only hi planes are written.
__global__ __launch_bounds__(256) void k_cvtT7(const void* s0, const void* s1,
                                               const void* s2, const void* s3,
                                               const void* s4, const void* s5,
                                               const void* s6,
                                               uint16_t* __restrict__ gdst,
                                               uint16_t* __restrict__ tail,
                                               const int* __restrict__ flag) {
    __shared__ float tile[64][65];
    int isf = flag[0];
    int z = blockIdx.z;
    const void* src = (z == 0) ? s0 : (z == 1) ? s1 : (z == 2) ? s2 :
                      (z == 3) ? s3 : (z == 4) ? s4 : (z == 5) ? s5 : s6;
    uint16_t* dh = (z == 0) ? gdst : tail + (size_t)(z - 1) * WSLOT;
    int k0 = blockIdx.x * 64, n0 = blockIdx.y * 64;
    for (int t = threadIdx.x; t < 4096; t += 256) {
        int r = t >> 6, c = t & 63;
        tile[r][c] = loadf(src, (size_t)(k0 + r) * DD + n0 + c, isf);
    }
    __syncthreads();
    for (int base = 0; base < 4096; base += 512) {
        int t = base + threadIdx.x * 2;
        int r = t >> 6, c = t & 63;
        float va = tile[c][r], vb = tile[c + 1][r];
        size_t o = (size_t)(n0 + r) * DD + k0 + c;
        *(u16x2*)(dh + o) = (u16x2){f2b(va), f2b(vb)};
    }
}

// =============== MFMA GEMM: C[M,768] = A[M,768] @ BT^T ====
// 128x128 tile, BK=32, 8 waves (512 thr): per-wave 32x64, acc=32 floats.
// LO: use lo-residual B pass (only when input fp32). DB: 2-phase double buffer.
enum { EPI_NONE = 0, EPI_BIAS_RELU = 3, EPI_BIAS = 4 };

template<int EPI, int ISF, int LO, int DB>
__device__ __forceinline__ void mgemm_core(
    const uint16_t* __restrict__ Az, const uint16_t* __restrict__ Bh,
    const uint16_t* __restrict__ Bl, const void* bias,
    uint16_t* __restrict__ Cz, uint16_t* As, uint16_t* Bs, int m0, int n0) {
    const int tid = threadIdx.x, lane = tid & 63;
    const int wid = tid >> 6;                  // 0..7
    const int wr = wid >> 1, wc = wid & 1;     // 4 M-quads x 2 N-halves
    constexpr int UL = (ISF && LO);            // use lo pass
    constexpr int BSZ = UL ? 8192 : 4096;      // per-buffer B size (u16)

    f32x4 acc[2][4];
    #pragma unroll
    for (int i = 0; i < 2; i++)
        #pragma unroll
        for (int j = 0; j < 4; j++) acc[i][j] = (f32x4){0.f, 0.f, 0.f, 0.f};

    // staging indices: 512 chunks of 16B cover a 128x32 tile (4 groups/row)
    const int scr = tid >> 2;                              // row 0..127
    const int sgl = (tid & 3) ^ ((scr >> 1) & 3);          // swizzled group
    const int sdst = tid * 8;

    int offA[2], offB[4];
    #pragma unroll
    for (int i = 0; i < 2; i++) {
        int r = wr * 32 + i * 16 + (lane & 15);
        offA[i] = r * 32 + (((lane >> 4) ^ ((r >> 1) & 3)) << 3);
    }
    #pragma unroll
    for (int j = 0; j < 4; j++) {
        int r = wc * 64 + j * 16 + (lane & 15);
        offB[j] = r * 32 + (((lane >> 4) ^ ((r >> 1) & 3)) << 3);
    }

    auto STAGE = [&](int buf, int k0) {
        gload16(Az + (size_t)(m0 + scr) * DD + k0 + sgl * 8, As + buf * 4096 + sdst);
        gload16(Bh + (size_t)(n0 + scr) * DD + k0 + sgl * 8, Bs + buf * BSZ + sdst);
        if (UL) gload16(Bl + (size_t)(n0 + scr) * DD + k0 + sgl * 8,
                        Bs + buf * BSZ + 4096 + sdst);
    };
    auto COMPUTE = [&](const uint16_t* Ac, const uint16_t* Bc) {
        bf16x8 af[2], b4[4], l4[4];
        #pragma unroll
        for (int i = 0; i < 2; i++) af[i] = *(const bf16x8*)(Ac + offA[i]);
        #pragma unroll
        for (int j = 0; j < 4; j++) {
            b4[j] = *(const bf16x8*)(Bc + offB[j]);
            if (UL) l4[j] = *(const bf16x8*)(Bc + 4096 + offB[j]);
        }
        #pragma unroll
        for (int i = 0; i < 2; i++)
            #pragma unroll
            for (int j = 0; j < 4; j++)
                acc[i][j] = __builtin_amdgcn_mfma_f32_16x16x32_bf16(af[i], b4[j], acc[i][j], 0, 0, 0);
        if (UL) {
            #pragma unroll
            for (int i = 0; i < 2; i++)
                #pragma unroll
                for (int j = 0; j < 4; j++)
                    acc[i][j] = __builtin_amdgcn_mfma_f32_16x16x32_bf16(af[i], l4[j], acc[i][j], 0, 0, 0);
        }
    };

    if (DB) {
        STAGE(0, 0);
        __syncthreads();
        int buf = 0;
        for (int t = 0; t < 24; ++t) {
            if (t < 23) STAGE(buf ^ 1, (t + 1) * 32);
            COMPUTE(As + buf * 4096, Bs + buf * BSZ);
            __syncthreads();
            buf ^= 1;
        }
    } else {
        for (int k0 = 0; k0 < DD; k0 += 32) {
            STAGE(0, k0);
            __syncthreads();
            COMPUTE(As, Bs);
            __syncthreads();
        }
    }
    // D layout: col = lane&15, row = (lane>>4)*4 + q
    #pragma unroll
    for (int i = 0; i < 2; i++) {
        #pragma unroll
        for (int j = 0; j < 4; j++) {
            int n = n0 + wc * 64 + j * 16 + (lane & 15);
            int mb = m0 + wr * 32 + i * 16 + ((lane >> 4) << 2);
            float bv = 0.f;
            if (EPI != EPI_NONE) bv = loadf(bias, n, ISF);
            #pragma unroll
            for (int q = 0; q < 4; q++) {
                float v = acc[i][j][q];
                if (EPI == EPI_BIAS_RELU) v = fmaxf(v + bv, 0.f);
                else if (EPI == EPI_BIAS) v = v + bv;
                Cz[(size_t)(mb + q) * DD + n] = f2b(v);
            }
        }
    }
}

template<int EPI, int LO, int DB>
__global__ __launch_bounds__(512, 4)
void k_mgemm(const uint16_t* __restrict__ A, uint32_t aZ,
             const uint16_t* __restrict__ BTh, uint32_t bZ,
             const void* bias0, const void* bias1, const void* bias2,
             uint16_t* __restrict__ C, uint32_t cZ,
             const int* __restrict__ flag) {
    __shared__ __align__(16) uint16_t As[(DB ? 2 : 1) * 4096];
    __shared__ __align__(16) uint16_t Bs[(DB ? 2 : 1) * (LO ? 2 : 1) * 4096];
    const int isf = flag[0];
    const int z = blockIdx.z;
    const uint16_t* Az = A + (size_t)z * aZ;
    const uint16_t* Bh = BTh + (size_t)z * bZ;
    const uint16_t* Bl = Bh + WMAT;
    uint16_t* Cz = C + (size_t)z * cZ;
    const void* bias = (z == 0) ? bias0 : (z == 1) ? bias1 : bias2;
    const int m0 = blockIdx.y * 128, n0 = blockIdx.x * 128;
    if (isf) mgemm_core<EPI, 1, LO, DB>(Az, Bh, Bl, bias, Cz, As, Bs, m0, n0);
    else     mgemm_core<EPI, 0, LO, DB>(Az, Bh, Bl, bias, Cz, As, Bs, m0, n0);
}

// =============== MFMA fused GRU layer: 3-gate GEMM (whh hi-only) + cell ====
// Tile M=128 x (3 gates x 64), 8 waves (512 thr): per-wave 32M x 32N/gate.
// 2-phase double-buffered staging (40KB LDS, 4 blocks/CU maintained).
template<int ISF>
__device__ __forceinline__ void grum_core(
    const uint16_t* __restrict__ X,
    const uint16_t* __restrict__ Wh,
    const void* __restrict__ bih, const void* __restrict__ bhh,
    const float* __restrict__ giE, uint16_t* __restrict__ Xn,
    uint16_t* As, uint16_t* Bs, int m0, int n0) {
    const int tid = threadIdx.x, lane = tid & 63;
    const int wid = tid >> 6;                  // 0..7
    const int wr = wid >> 1, wc = wid & 1;     // 4 M-quads x 2 N-halves

    f32x4 acc[3][2][2];
    #pragma unroll
    for (int gg = 0; gg < 3; gg++)
        #pragma unroll
        for (int i = 0; i < 2; i++)
            #pragma unroll
            for (int j = 0; j < 2; j++) acc[gg][i][j] = (f32x4){0.f, 0.f, 0.f, 0.f};

    // A staging: 512 chunks cover 128x32
    const int acr = tid >> 2;
    const int agl = (tid & 3) ^ ((acr >> 1) & 3);
    // B staging: threads 0..255 stage 3 gates (hi only), 256 chunks per gate
    const int bc = tid & 255;
    const int bcr = bc >> 2;
    const int bgl = (bc & 3) ^ ((bcr >> 1) & 3);

    int offA[2], offB[2];
    #pragma unroll
    for (int i = 0; i < 2; i++) {
        int r = wr * 32 + i * 16 + (lane & 15);
        offA[i] = r * 32 + (((lane >> 4) ^ ((r >> 1) & 3)) << 3);
    }
    #pragma unroll
    for (int j = 0; j < 2; j++) {
        int r = wc * 32 + j * 16 + (lane & 15);
        offB[j] = r * 32 + (((lane >> 4) ^ ((r >> 1) & 3)) << 3);
    }

    auto STAGE = [&](int buf, int k0) {
        gload16(X + (size_t)(m0 + acr) * DD + k0 + agl * 8, As + buf * 4096 + tid * 8);
        if (tid < 256) {
            #pragma unroll
            for (int gg = 0; gg < 3; gg++)
                gload16(Wh + (size_t)(gg * DD + n0 + bcr) * DD + k0 + bgl * 8,
                        Bs + buf * 6144 + gg * 2048 + bc * 8);
        }
    };
    auto COMPUTE = [&](const uint16_t* Ac, const uint16_t* Bc) {
        bf16x8 af[2];
        #pragma unroll
        for (int i = 0; i < 2; i++) af[i] = *(const bf16x8*)(Ac + offA[i]);
        #pragma unroll
        for (int gg = 0; gg < 3; gg++) {
            const uint16_t* Bhc = Bc + gg * 2048;
            bf16x8 bh2[2];
            #pragma unroll
            for (int j = 0; j < 2; j++) bh2[j] = *(const bf16x8*)(Bhc + offB[j]);
            #pragma unroll
            for (int j = 0; j < 2; j++)
                #pragma unroll
                for (int i = 0; i < 2; i++)
                    acc[gg][i][j] = __builtin_amdgcn_mfma_f32_16x16x32_bf16(af[i], bh2[j], acc[gg][i][j], 0, 0, 0);
        }
    };

    STAGE(0, 0);
    __syncthreads();
    int buf = 0;
    for (int t = 0; t < 24; ++t) {
        if (t < 23) STAGE(buf ^ 1, (t + 1) * 32);
        COMPUTE(As + buf * 4096, Bs + buf * 6144);
        __syncthreads();
        buf ^= 1;
    }
    // epilogue: full GRU cell pointwise
    #pragma unroll
    for (int j = 0; j < 2; j++) {
        int n = n0 + wc * 32 + j * 16 + (lane & 15);
        float bh0 = loadf(bhh, n, ISF);
        float bh1 = loadf(bhh, DD + n, ISF);
        float bh2v = loadf(bhh, 2 * DD + n, ISF);
        float gE0 = giE[n], gE1 = giE[DD + n], gE2 = giE[2 * DD + n];
        float bi0 = loadf(bih, n, ISF);
        float bi1 = loadf(bih, DD + n, ISF);
        float bi2 = loadf(bih, 2 * DD + n, ISF);
        #pragma unroll
        for (int i = 0; i < 2; i++) {
            int mb = m0 + wr * 32 + i * 16 + ((lane >> 4) << 2);
            #pragma unroll
            for (int q = 0; q < 4; q++) {
                int m = mb + q;
                bool msg = (m < SS);
                float gr = msg ? gE0 : bi0;
                float gz = msg ? gE1 : bi1;
                float gn = msg ? gE2 : bi2;
                float rg = 1.f / (1.f + expf(-(acc[0][i][j][q] + bh0 + gr)));
                float zg = 1.f / (1.f + expf(-(acc[1][i][j][q] + bh1 + gz)));
                float hn = acc[2][i][j][q] + bh2v;
                float nn = tanhf(gn + rg * hn);
                float xo = b2f(X[(size_t)m * DD + n]);
                Xn[(size_t)m * DD + n] = f2b((1.f - zg) * nn + zg * xo);
            }
        }
    }
}

__global__ __launch_bounds__(512, 4)
void k_grum(const uint16_t* __restrict__ X,
            const uint16_t* __restrict__ Wh,
            const void* __restrict__ bih, const void* __restrict__ bhh,
            const float* __restrict__ giE, uint16_t* __restrict__ Xn,
            const int* __restrict__ flag) {
    __shared__ __align__(16) uint16_t As[2 * 4096];      // dbuf 128x32 (16KB)
    __shared__ __align__(16) uint16_t Bs[2 * 3 * 2048];  // dbuf 3 gates x 64x32 (24KB)
    const int n0 = blockIdx.x * 64, m0 = blockIdx.y * 128;
    if (flag[0]) grum_core<1>(X, Wh, bih, bhh, giE, Xn, As, Bs, m0, n0);
    else         grum_core<0>(X, Wh, bih, bhh, giE, Xn, As, Bs, m0, n0);
}

// ============================== driver ==============================
extern "C" void kernel_launch(void* const* d_in, const int* in_sizes, int n_in,
                              void* d_out, int out_size, void* d_ws, size_t ws_size,
                              hipStream_t stream) {
    float* OUTF = (float*)d_out;            // FINAL output: fp32
    uint16_t* OB = (uint16_t*)d_out;        // first 18.9MB of d_out as bf16 trunk/H scratch

    static const int expect[29] = {
        3145728,3145728,3145728,3145728, 589824,768, 1179648, 1769472,1769472, 2304,2304,
        589824,768,589824,768,768,768,
        589824,768,589824,768,768,768,
        589824,768,589824,768,768,768 };
    int bad = -1;
    if (n_in != 29) bad = 90;
    else { for (int i = 0; i < 29; i++) if (in_sizes[i] != expect[i]) { bad = i; break; } }
    if (bad < 0 && out_size != (int)TOTAL_ND) bad = 91;
    if (bad < 0 && ws_size < 33ull * 1024 * 1024) bad = 92;
    if (bad >= 0) {
        k_diag<<<1, 64, 0, stream>>>(OUTF, 10000.f + 100.f * (float)bad);
        return;
    }

    // ws layout (floats): small scratch | F128 hi/lo | W0 | WH | WT  (~30.8 MiB)
    float* fbase = (float*)d_ws;
    float* simb = fbase;                        // 16384
    float* mnmx = simb + 16384;                 // 2
    float* deg  = mnmx + 2;                     // 128
    float* dinv = deg + 128;                    // 128
    float* aggb = dinv + 128;                   // 98304
    float* svec = aggb + 98304;                 // 768
    float* mvec = svec + 768;                   // 768
    float* giE  = mvec + 768;                   // 2304
    int*   flag = (int*)(giE + 2304);           // 1
    uint16_t* F128h = (uint16_t*)(fbase + 118916);  // 98304 u16
    uint16_t* F128l = (uint16_t*)(fbase + 168068);  // 98304 u16
    uint16_t* W0 = (uint16_t*)(fbase + 217220);     // 9,437,184 u16
    uint16_t* WH = W0 + TOTAL_ND;                   // 3,145,728 u16 slots
    uint16_t* WT = WH + NBSD;                       // 3,145,728 u16 slots (spare)

    // head weights (hi-only) live in the TAIL of d_out (dead until final LN)
    uint16_t* tailW = (uint16_t*)((char*)d_out + 23592960);  // 6 slots x WSLOT

    const void* hf = d_in[0];
    const void* hc = d_in[1];
    const void* hd = d_in[2];
    const void* hs = d_in[3];

    k_probe<<<1, 64, 0, stream>>>(hf, flag);

    // ---- all transpose-weight conversions batched (gcn_W -> WH, heads -> tail) ----
    k_cvtT7<<<dim3(12, 12, 7), 256, 0, stream>>>(
        d_in[4], d_in[11], d_in[13], d_in[17], d_in[19], d_in[23], d_in[25],
        WH, tailW, flag);

    // ---- GCN front-end ----
    k_build_all<<<3456, 256, 0, stream>>>(hc, hd, hs, W0, F128h, F128l, flag);
    k_simgemm<<<dim3(2, 2), 256, 0, stream>>>(F128h, F128l, simb);
    k_simpost<<<1, 256, 0, stream>>>(simb, mnmx);
    k_deg<<<SS, SS, 0, stream>>>(simb, mnmx, deg, dinv);
    // trunk xw GEMM: gcn_W hi-only (LO=0), double-buffered (DB=1)
    k_mgemm<EPI_NONE, 0, 1><<<dim3(6, 96, 1), 512, 0, stream>>>(
        W0, 0, WH, 0, nullptr, nullptr, nullptr, OB, 0, flag);
    k_agg<<<dim3(SS, 3), 256, 0, stream>>>(simb, dinv, OB, aggb);
    k_gcn_combine<<<4608, 256, 0, stream>>>(OB, aggb, deg, d_in[5], flag);

    // ---- GatedGraphConv: whh -> WH bf16 hi only (gcn_W in WH now dead) ----
    k_cvt1<<<1728, 256, 0, stream>>>(d_in[8], WH, 1769472, flag);

    k_colsum<<<12, 256, 0, stream>>>(OB, svec, mvec);
    k_matvec<<<dim3(3, 16), 256, 0, stream>>>(svec, d_in[6], 0, mvec, flag);
    k_rowdot<<<2304, 256, 0, stream>>>(mvec, d_in[7], d_in[9], giE, flag);
    k_grum<<<dim3(12, 96), 512, 0, stream>>>(OB, WH, d_in[9], d_in[10], giE, W0, flag);

    k_colsum<<<12, 256, 0, stream>>>(W0, svec, mvec);
    k_matvec<<<dim3(3, 16), 256, 0, stream>>>(svec, d_in[6], (size_t)DD * DD, mvec, flag);
    k_rowdot<<<2304, 256, 0, stream>>>(mvec, d_in[7], d_in[9], giE, flag);
    k_grum<<<dim3(12, 96), 512, 0, stream>>>(W0, WH, d_in[9], d_in[10], giE, OB, flag);

    // ---- y = hf + relu(x) for all 3 chunks (OB -> W0); OB then dead ----
    k_build_y<<<4608, 256, 0, stream>>>(hf, OB, W0, flag);

    // ---- heads batched over z: y(W0) -> H(OB) -> T(W0) -> LN(d_out) ----
    // head weights hi-only (LO=0) + double-buffered (DB=1)
    k_mgemm<EPI_BIAS_RELU, 0, 1><<<dim3(6, 32, 3), 512, 0, stream>>>(
        W0, NBSD, tailW, 2 * WSLOT, d_in[12], d_in[18], d_in[24], OB, NBSD, flag);
    k_mgemm<EPI_BIAS, 0, 1><<<dim3(6, 32, 3), 512, 0, stream>>>(
        OB, NBSD, tailW + WSLOT, 2 * WSLOT, d_in[14], d_in[20], d_in[26], W0, NBSD, flag);
    k_ln<<<NNODE, 256, 0, stream>>>(W0, d_in[15], d_in[16], d_in[21], d_in[22],
                                    d_in[27], d_in[28], OUTF, flag);
}